// Round 1
// baseline (4067.149 us; speedup 1.0000x reference)
//
#include <hip/hip_runtime.h>

// Problem constants (Bert4KGModel): B=4, T=S=512, D=1024, H=16, dh=64, F=4096, L=2
#define BB  4
#define TT  512
#define DD  1024
#define HH  16
#define DHH 64
#define FF  4096

typedef unsigned short u16;
typedef __attribute__((ext_vector_type(8))) short bfrag8;   // 8 bf16 (4 VGPRs)
typedef __attribute__((ext_vector_type(4))) float facc4;    // 4 f32 acc

__device__ __forceinline__ u16 f2bf(float f){
  unsigned u = __float_as_uint(f);
  unsigned r = u + 0x7fffu + ((u >> 16) & 1u);   // RNE
  return (u16)(r >> 16);
}
__device__ __forceinline__ float bf2f(u16 h){
  return __uint_as_float(((unsigned)h) << 16);
}

// ---------------------------------------------------------------------------
// Weight transpose + f32->bf16: W[z][R][C] f32  ->  Wt[z][C][R] bf16
// ---------------------------------------------------------------------------
__global__ __launch_bounds__(256) void transpose_w_kernel(
    const float* __restrict__ W, u16* __restrict__ Wt, int R, int C)
{
  __shared__ float tile[32][33];
  const int tx = threadIdx.x & 31, ty = threadIdx.x >> 5;   // 32 x 8
  const long zo = (long)blockIdx.z * R * C;
  const int c0 = blockIdx.x << 5, r0 = blockIdx.y << 5;
  #pragma unroll
  for (int i = 0; i < 4; ++i)
    tile[ty + i*8][tx] = W[zo + (long)(r0 + ty + i*8)*C + c0 + tx];
  __syncthreads();
  #pragma unroll
  for (int i = 0; i < 4; ++i)
    Wt[zo + (long)(c0 + ty + i*8)*R + r0 + tx] = f2bf(tile[tx][ty + i*8]);
}

// ---------------------------------------------------------------------------
// Elementwise f32 -> bf16 (vectorized)
// ---------------------------------------------------------------------------
__global__ __launch_bounds__(256) void f32_to_bf16_kernel(
    const float* __restrict__ in, u16* __restrict__ out, int n4)
{
  int i = blockIdx.x * 256 + threadIdx.x;
  if (i >= n4) return;
  float4 v = ((const float4*)in)[i];
  ushort4 o;
  o.x = f2bf(v.x); o.y = f2bf(v.y); o.z = f2bf(v.z); o.w = f2bf(v.w);
  ((ushort4*)out)[i] = o;
}

// ---------------------------------------------------------------------------
// Embedding gather: e[row] = emb[idx[row]]*32 + pos[row%T]   (32 = sqrt(1024))
// ---------------------------------------------------------------------------
__global__ __launch_bounds__(256) void embed_kernel(
    const float* __restrict__ emb, const int* __restrict__ pvec,
    const float* __restrict__ pos, float* __restrict__ out)
{
  const int row = blockIdx.x;
  const int i = threadIdx.x;
  const int idx = pvec[row];
  const int t = row & (TT - 1);
  float4 e = ((const float4*)(emb + (long)idx * DD))[i];
  float4 p = ((const float4*)(pos + (long)t * DD))[i];
  float4 o;
  o.x = e.x * 32.0f + p.x; o.y = e.y * 32.0f + p.y;
  o.z = e.z * 32.0f + p.z; o.w = e.w * 32.0f + p.w;
  ((float4*)(out + (long)row * DD))[i] = o;
}

// ---------------------------------------------------------------------------
// LayerNorm(a [+ res]) -> yf (f32, optional) and yb (bf16). One block per row.
// ---------------------------------------------------------------------------
__global__ __launch_bounds__(256) void ln_kernel(
    const float* __restrict__ a, const float* __restrict__ res,
    float* __restrict__ yf, u16* __restrict__ yb)
{
  const int row = blockIdx.x;
  const int i = threadIdx.x;
  const int lane = i & 63, wid = i >> 6;
  float4 x = ((const float4*)(a + (long)row * DD))[i];
  if (res){
    float4 r4 = ((const float4*)(res + (long)row * DD))[i];
    x.x += r4.x; x.y += r4.y; x.z += r4.z; x.w += r4.w;
  }
  float s = x.x + x.y + x.z + x.w;
  #pragma unroll
  for (int o = 32; o; o >>= 1) s += __shfl_xor(s, o);
  __shared__ float red[4];
  if (lane == 0) red[wid] = s;
  __syncthreads();
  const float mean = (red[0] + red[1] + red[2] + red[3]) * (1.0f / DD);
  __syncthreads();
  const float dx = x.x - mean, dy = x.y - mean, dz = x.z - mean, dw = x.w - mean;
  float q = dx*dx + dy*dy + dz*dz + dw*dw;
  #pragma unroll
  for (int o = 32; o; o >>= 1) q += __shfl_xor(q, o);
  if (lane == 0) red[wid] = q;
  __syncthreads();
  const float var = (red[0] + red[1] + red[2] + red[3]) * (1.0f / DD);
  const float rstd = rsqrtf(var + 1e-5f);
  float4 y; y.x = dx*rstd; y.y = dy*rstd; y.z = dz*rstd; y.w = dw*rstd;
  if (yf) ((float4*)(yf + (long)row * DD))[i] = y;
  ushort4 o4; o4.x = f2bf(y.x); o4.y = f2bf(y.y); o4.z = f2bf(y.z); o4.w = f2bf(y.w);
  ((ushort4*)(yb + (long)row * DD))[i] = o4;
}

// ---------------------------------------------------------------------------
// Masked softmax, in-place on bf16 scores [B*H*T rows of S=512].
// mode < 0: causal (col <= row%T).  mode >= 0: (context_mask[b][col] != mode).
// One wave per row (8 elems/lane).
// ---------------------------------------------------------------------------
__global__ __launch_bounds__(256) void softmax_kernel(
    u16* __restrict__ P, const int* __restrict__ cmask, int mode)
{
  const long rid = (long)blockIdx.x * 4 + (threadIdx.x >> 6);
  const int lane = threadIdx.x & 63;
  const int t = (int)(rid & (TT - 1));
  const int b = (int)(rid >> 13);          // rid / (H*T) = rid / 8192
  u16* row = P + rid * TT;
  union { int4 v; u16 u[8]; } U;
  U.v = ((const int4*)row)[lane];
  const int sbase = lane * 8;
  float p[8];
  float m = -3e38f;
  #pragma unroll
  for (int j = 0; j < 8; ++j){
    float v = bf2f(U.u[j]);
    bool ok = (mode < 0) ? (sbase + j <= t)
                         : (cmask[b * TT + sbase + j] != mode);
    v = ok ? v : -1e20f;
    p[j] = v;
    m = fmaxf(m, v);
  }
  #pragma unroll
  for (int o = 32; o; o >>= 1) m = fmaxf(m, __shfl_xor(m, o));
  float s = 0.0f;
  #pragma unroll
  for (int j = 0; j < 8; ++j){ p[j] = __expf(p[j] - m); s += p[j]; }
  #pragma unroll
  for (int o = 32; o; o >>= 1) s += __shfl_xor(s, o);
  const float inv = 1.0f / s;
  #pragma unroll
  for (int j = 0; j < 8; ++j) U.u[j] = f2bf(p[j] * inv);
  ((int4*)row)[lane] = U.v;
}

// ---------------------------------------------------------------------------
// Generic bf16 MFMA GEMM:  C[m][n] = alpha * ( sum_k A[m][k]*B[n][k] + bias[n] )
// A: [M][K] row-major (lda), B: [N][K] row-major (ldb) (i.e. B-transposed).
// Batched via blockIdx.z: A += z*zsA, B += z*zsB,
// C base = (z/zdiv)*czs1 + (z%zdiv)*czs2.
// outmode 0: off = cbase + m*ldc + n  (writes Cf f32 and/or Cb bf16)
// outmode 1: Q/K layout  [b][h][t][d]  from m=b*T+t, n=h*dh+d   (Cb only)
// outmode 2: V^T layout  [b][h][d][s]  from m=b*S+s, n=h*dh+d   (Cb only)
// ---------------------------------------------------------------------------
template<int BM, int BN>
__global__ __launch_bounds__(256) void gemm_bt(
    const u16* __restrict__ A, const u16* __restrict__ B,
    const float* __restrict__ bias,
    float* __restrict__ Cf, u16* __restrict__ Cb,
    int K, int lda, int ldb, int ldc,
    long zsA, long zsB, int zdiv, long czs1, long czs2,
    int outmode, int relu, float alpha)
{
  constexpr int BK = 32;
  constexpr int LS = 40;                      // padded LDS row stride (bank-spread)
  __shared__ __align__(16) u16 As[BM * LS];
  __shared__ __align__(16) u16 Bs[BN * LS];
  const int z = blockIdx.z;
  const u16* Ab = A + (long)z * zsA;
  const u16* Bb = B + (long)z * zsB;
  const long cbase = (long)(z / zdiv) * czs1 + (long)(z % zdiv) * czs2;
  const int tid = threadIdx.x;
  const int lane = tid & 63, wid = tid >> 6;
  const int m0 = blockIdx.y * BM, n0 = blockIdx.x * BN;
  constexpr int WGN = (BN >= 128) ? 2 : 1;    // wave grid
  constexpr int WGM = 4 / WGN;
  constexpr int TMW = BM / WGM, TNW = BN / WGN;
  constexpr int FM = TMW / 16, FN = TNW / 16;
  const int wm = (wid / WGN) * TMW;
  const int wn = (wid % WGN) * TNW;
  facc4 acc[FM][FN] = {};
  constexpr int APASS = BM / 64, BPASS = BN / 64;  // 256 thr × 16B = 64 rows/pass
  const int crow = tid >> 2, ckc = tid & 3;
  const int fr = lane & 15, kg = lane >> 4;

  for (int k0 = 0; k0 < K; k0 += BK){
    int4 va[APASS], vb[BPASS];
    #pragma unroll
    for (int p = 0; p < APASS; ++p)
      va[p] = *(const int4*)(Ab + (long)(m0 + p*64 + crow) * lda + (k0 + ckc*8));
    #pragma unroll
    for (int p = 0; p < BPASS; ++p)
      vb[p] = *(const int4*)(Bb + (long)(n0 + p*64 + crow) * ldb + (k0 + ckc*8));
    __syncthreads();                          // prev iter's LDS reads done
    #pragma unroll
    for (int p = 0; p < APASS; ++p)
      *(int4*)&As[(p*64 + crow) * LS + ckc*8] = va[p];
    #pragma unroll
    for (int p = 0; p < BPASS; ++p)
      *(int4*)&Bs[(p*64 + crow) * LS + ckc*8] = vb[p];
    __syncthreads();                          // tile visible
    bfrag8 af[FM], bf[FN];
    #pragma unroll
    for (int i = 0; i < FM; ++i)
      af[i] = *(const bfrag8*)&As[(wm + i*16 + fr) * LS + kg*8];
    #pragma unroll
    for (int j = 0; j < FN; ++j)
      bf[j] = *(const bfrag8*)&Bs[(wn + j*16 + fr) * LS + kg*8];
    #pragma unroll
    for (int i = 0; i < FM; ++i)
      #pragma unroll
      for (int j = 0; j < FN; ++j)
        acc[i][j] = __builtin_amdgcn_mfma_f32_16x16x32_bf16(af[i], bf[j], acc[i][j], 0, 0, 0);
  }

  // Epilogue. C/D layout: col = lane&15 (fr), row = (lane>>4)*4 + reg (kg).
  #pragma unroll
  for (int i = 0; i < FM; ++i){
    #pragma unroll
    for (int j = 0; j < FN; ++j){
      const int gn = n0 + wn + j*16 + fr;
      const float bv = bias ? bias[gn] : 0.0f;
      #pragma unroll
      for (int rr = 0; rr < 4; ++rr){
        const int gm = m0 + wm + i*16 + kg*4 + rr;
        float v = (acc[i][j][rr] + bv) * alpha;
        if (relu) v = fmaxf(v, 0.0f);
        long off;
        if (outmode == 0)
          off = cbase + (long)gm * ldc + gn;
        else if (outmode == 1)   // [b][h][t][d]
          off = (((long)(gm >> 9) * HH + (gn >> 6)) * TT + (gm & (TT-1))) * DHH + (gn & (DHH-1));
        else                      // [b][h][d][s]
          off = (((long)(gm >> 9) * HH + (gn >> 6)) * DHH + (gn & (DHH-1))) * TT + (gm & (TT-1));
        if (Cf) Cf[off] = v;
        if (Cb) Cb[off] = f2bf(v);
      }
    }
  }
}

// ---------------------------------------------------------------------------
extern "C" void kernel_launch(void* const* d_in, const int* in_sizes, int n_in,
                              void* d_out, int out_size, void* d_ws, size_t ws_size,
                              hipStream_t stream)
{
  (void)in_sizes; (void)n_in; (void)out_size; (void)ws_size;
  const float* emb   = (const float*)d_in[0];
  const int*   pvec  = (const int*)d_in[1];
  const float* g_enc = (const float*)d_in[2];
  const float* g_con = (const float*)d_in[3];
  const float* g_db  = (const float*)d_in[4];
  const float* g_usr = (const float*)d_in[5];
  const int*   cmask = (const int*)d_in[6];
  const float* pose  = (const float*)d_in[7];
  const float* Wq = (const float*)d_in[8];
  const float* bq = (const float*)d_in[9];
  const float* Wk = (const float*)d_in[10];
  const float* bk = (const float*)d_in[11];
  const float* Wv = (const float*)d_in[12];
  const float* bv = (const float*)d_in[13];
  const float* Wo = (const float*)d_in[14];
  const float* bo = (const float*)d_in[15];
  const float* W1 = (const float*)d_in[16];
  const float* b1 = (const float*)d_in[17];
  const float* W2 = (const float*)d_in[18];
  const float* b2 = (const float*)d_in[19];
  float* out = (float*)d_out;

  const size_t NTOK = (size_t)BB * TT;   // 2048 (= B*T = B*S)

  char* wp = (char*)d_ws;
  auto alloc = [&](size_t bytes) -> char* {
    char* p = wp;
    wp += (bytes + 255) & ~(size_t)255;
    return p;
  };
  u16*   WqT  = (u16*)  alloc(sizeof(u16) * 10 * DD * DD);
  u16*   WkT  = (u16*)  alloc(sizeof(u16) * 10 * DD * DD);
  u16*   WvT  = (u16*)  alloc(sizeof(u16) * 10 * DD * DD);
  u16*   WoT  = (u16*)  alloc(sizeof(u16) * 10 * DD * DD);
  u16*   W1T  = (u16*)  alloc(sizeof(u16) * 2 * DD * FF);
  u16*   W2T  = (u16*)  alloc(sizeof(u16) * 2 * DD * FF);
  u16*   kvbE = (u16*)  alloc(sizeof(u16) * NTOK * DD);
  u16*   kvbC = (u16*)  alloc(sizeof(u16) * NTOK * DD);
  u16*   kvbD = (u16*)  alloc(sizeof(u16) * NTOK * DD);
  u16*   kvbU = (u16*)  alloc(sizeof(u16) * NTOK * DD);
  float* xf   = (float*)alloc(sizeof(float) * NTOK * DD);
  u16*   xb   = (u16*)  alloc(sizeof(u16) * NTOK * DD);
  u16*   Qb   = (u16*)  alloc(sizeof(u16) * NTOK * DD);
  u16*   Kb   = (u16*)  alloc(sizeof(u16) * NTOK * DD);
  u16*   Vtb  = (u16*)  alloc(sizeof(u16) * NTOK * DD);
  u16*   scr  = (u16*)  alloc(sizeof(u16) * (size_t)BB * HH * TT * TT);
  u16*   attnb= (u16*)  alloc(sizeof(u16) * NTOK * DD);
  float* obuf = (float*)alloc(sizeof(float) * NTOK * DD);
  u16*   hb   = (u16*)  alloc(sizeof(u16) * NTOK * FF);

  // ---- per-call weight prep: transpose to [Dout][Din] bf16 ----
  transpose_w_kernel<<<dim3(DD/32, DD/32, 10), 256, 0, stream>>>(Wq, WqT, DD, DD);
  transpose_w_kernel<<<dim3(DD/32, DD/32, 10), 256, 0, stream>>>(Wk, WkT, DD, DD);
  transpose_w_kernel<<<dim3(DD/32, DD/32, 10), 256, 0, stream>>>(Wv, WvT, DD, DD);
  transpose_w_kernel<<<dim3(DD/32, DD/32, 10), 256, 0, stream>>>(Wo, WoT, DD, DD);
  transpose_w_kernel<<<dim3(FF/32, DD/32, 2), 256, 0, stream>>>(W1, W1T, DD, FF);
  transpose_w_kernel<<<dim3(DD/32, FF/32, 2), 256, 0, stream>>>(W2, W2T, FF, DD);

  const int n4 = (int)(NTOK * DD / 4);
  f32_to_bf16_kernel<<<n4/256, 256, 0, stream>>>(g_enc, kvbE, n4);
  f32_to_bf16_kernel<<<n4/256, 256, 0, stream>>>(g_con, kvbC, n4);
  f32_to_bf16_kernel<<<n4/256, 256, 0, stream>>>(g_db,  kvbD, n4);
  f32_to_bf16_kernel<<<n4/256, 256, 0, stream>>>(g_usr, kvbU, n4);

  // ---- embedding + initial LN ----
  embed_kernel<<<(int)NTOK, 256, 0, stream>>>(emb, pvec, pose, obuf);
  ln_kernel<<<(int)NTOK, 256, 0, stream>>>(obuf, nullptr, xf, xb);

  const u16* kvTab[5]  = {xb, kvbD, kvbC, kvbU, kvbE};
  const int  modeTab[5] = {-1, 2, 1, 3, 0};   // causal, !=DBPEDIA, !=CONCEPT, !=USER, !=PAD

  const dim3 gProj(DD/128, (int)NTOK/128, 1);   // 2048x1024, K=1024
  const dim3 gQK(TT/128, TT/128, BB*HH);        // 512x512,  K=64,  batch 64
  const dim3 gPV(1, TT/128, BB*HH);             // 512x64,   K=512, batch 64
  const dim3 gF1(FF/128, (int)NTOK/128, 1);     // 2048x4096, K=1024
  const dim3 gF2(DD/128, (int)NTOK/128, 1);     // 2048x1024, K=4096

  for (int l = 0; l < 2; ++l){
    for (int i = 0; i < 5; ++i){
      const u16* kvb = kvTab[i];
      const size_t wo  = (size_t)(l*5 + i) * DD * DD;
      const size_t bof = (size_t)(l*5 + i) * DD;
      // Q = (x @ Wq + bq) / 8   -> [b][h][t][d]
      gemm_bt<128,128><<<gProj, 256, 0, stream>>>(
        xb, WqT + wo, bq + bof, nullptr, Qb,
        DD, DD, DD, 0, 0, 0, 1, 0, 0, 1, 0, 0.125f);
      // K = kv @ Wk + bk        -> [b][h][t][d]
      gemm_bt<128,128><<<gProj, 256, 0, stream>>>(
        kvb, WkT + wo, bk + bof, nullptr, Kb,
        DD, DD, DD, 0, 0, 0, 1, 0, 0, 1, 0, 1.0f);
      // V = kv @ Wv + bv        -> [b][h][d][s]  (transposed for PV)
      gemm_bt<128,128><<<gProj, 256, 0, stream>>>(
        kvb, WvT + wo, bv + bof, nullptr, Vtb,
        DD, DD, DD, 0, 0, 0, 1, 0, 0, 2, 0, 1.0f);
      // scores = Q @ K^T  (batched over b*h), bf16 out
      gemm_bt<128,128><<<gQK, 256, 0, stream>>>(
        Qb, Kb, nullptr, nullptr, scr,
        DHH, DHH, DHH, TT, (long)TT*DHH, (long)TT*DHH,
        1 << 30, 0, (long)TT*TT, 0, 0, 1.0f);
      // masked softmax in-place
      softmax_kernel<<<BB*HH*TT/4, 256, 0, stream>>>(scr, cmask, modeTab[i]);
      // attn = P @ V   -> [B*T][D] bf16
      gemm_bt<128,64><<<gPV, 256, 0, stream>>>(
        scr, Vtb, nullptr, nullptr, attnb,
        TT, TT, TT, DD, (long)TT*TT, (long)DHH*TT,
        HH, (long)TT*DD, (long)DHH, 0, 0, 1.0f);
      // O-projection (f32 out for residual)
      gemm_bt<128,128><<<gProj, 256, 0, stream>>>(
        attnb, WoT + wo, bo + bof, obuf, nullptr,
        DD, DD, DD, DD, 0, 0, 1, 0, 0, 0, 0, 1.0f);
      // x = LN(x + attn_out)
      ln_kernel<<<(int)NTOK, 256, 0, stream>>>(obuf, xf, xf, xb);
    }
    // FFN
    gemm_bt<128,128><<<gF1, 256, 0, stream>>>(
      xb, W1T + (size_t)l*DD*FF, b1 + (size_t)l*FF, nullptr, hb,
      DD, DD, DD, FF, 0, 0, 1, 0, 0, 0, 1, 1.0f);
    gemm_bt<128,128><<<gF2, 256, 0, stream>>>(
      hb, W2T + (size_t)l*DD*FF, b2 + (size_t)l*DD, obuf, nullptr,
      FF, FF, FF, DD, 0, 0, 1, 0, 0, 0, 0, 1.0f);
    float* yf = (l == 1) ? out : xf;
    ln_kernel<<<(int)NTOK, 256, 0, stream>>>(obuf, xf, yf, xb);
  }
}

// Round 2
// 1890.294 us; speedup vs baseline: 2.1516x; 2.1516x over previous
//
#include <hip/hip_runtime.h>

// Problem constants (Bert4KGModel): B=4, T=S=512, D=1024, H=16, dh=64, F=4096, L=2
#define BB  4
#define TT  512
#define DD  1024
#define HH  16
#define DHH 64
#define FF  4096

typedef unsigned short u16;
typedef __attribute__((ext_vector_type(8))) short bfrag8;   // 8 bf16 (4 VGPRs)
typedef __attribute__((ext_vector_type(4))) float facc4;    // 4 f32 acc

__device__ __forceinline__ u16 f2bf(float f){
  unsigned u = __float_as_uint(f);
  unsigned r = u + 0x7fffu + ((u >> 16) & 1u);   // RNE
  return (u16)(r >> 16);
}
__device__ __forceinline__ float bf2f(u16 h){
  return __uint_as_float(((unsigned)h) << 16);
}

// async global->LDS, 16B per lane; LDS dest is wave-uniform base + lane*16
__device__ __forceinline__ void gload16(const u16* g, u16* l){
  __builtin_amdgcn_global_load_lds(
      (const __attribute__((address_space(1))) void*)g,
      (__attribute__((address_space(3))) void*)l, 16, 0, 0);
}

// ---------------------------------------------------------------------------
// Weight transpose + f32->bf16 with generalized z-mapping:
//   src = W + (z/zdiv)*szs1 + (z%zdiv)*szs2   (R x C, row-major f32)
//   dst = Wt + (z/zdiv)*dzs1 + (z%zdiv)*dzs2  (C x R, row-major bf16)
// ---------------------------------------------------------------------------
__global__ __launch_bounds__(256) void transpose_w_kernel(
    const float* __restrict__ W, u16* __restrict__ Wt, int R, int C,
    long szs1, long szs2, long dzs1, long dzs2, int zdiv)
{
  __shared__ float tile[32][33];
  const int tx = threadIdx.x & 31, ty = threadIdx.x >> 5;   // 32 x 8
  const int z = blockIdx.z;
  const long so = (long)(z / zdiv) * szs1 + (long)(z % zdiv) * szs2;
  const long dzo = (long)(z / zdiv) * dzs1 + (long)(z % zdiv) * dzs2;
  const int c0 = blockIdx.x << 5, r0 = blockIdx.y << 5;
  #pragma unroll
  for (int i = 0; i < 4; ++i)
    tile[ty + i*8][tx] = W[so + (long)(r0 + ty + i*8)*C + c0 + tx];
  __syncthreads();
  #pragma unroll
  for (int i = 0; i < 4; ++i)
    Wt[dzo + (long)(c0 + ty + i*8)*R + r0 + tx] = f2bf(tile[tx][ty + i*8]);
}

// ---------------------------------------------------------------------------
// 4 buffers f32 -> bf16 in one launch (blockIdx.y selects buffer)
// ---------------------------------------------------------------------------
__global__ __launch_bounds__(256) void f32_to_bf16_4(
    const float* __restrict__ a0, const float* __restrict__ a1,
    const float* __restrict__ a2, const float* __restrict__ a3,
    u16* __restrict__ o0, u16* __restrict__ o1,
    u16* __restrict__ o2, u16* __restrict__ o3, int n4)
{
  const float* s; u16* d;
  switch (blockIdx.y){
    case 0: s = a0; d = o0; break;
    case 1: s = a1; d = o1; break;
    case 2: s = a2; d = o2; break;
    default: s = a3; d = o3; break;
  }
  int i = blockIdx.x * 256 + threadIdx.x;
  if (i >= n4) return;
  float4 v = ((const float4*)s)[i];
  ushort4 o;
  o.x = f2bf(v.x); o.y = f2bf(v.y); o.z = f2bf(v.z); o.w = f2bf(v.w);
  ((ushort4*)d)[i] = o;
}

// ---------------------------------------------------------------------------
// Embedding gather: e[row] = emb[idx[row]]*32 + pos[row%T]
// ---------------------------------------------------------------------------
__global__ __launch_bounds__(256) void embed_kernel(
    const float* __restrict__ emb, const int* __restrict__ pvec,
    const float* __restrict__ pos, float* __restrict__ out)
{
  const int row = blockIdx.x;
  const int i = threadIdx.x;
  const int idx = pvec[row];
  const int t = row & (TT - 1);
  float4 e = ((const float4*)(emb + (long)idx * DD))[i];
  float4 p = ((const float4*)(pos + (long)t * DD))[i];
  float4 o;
  o.x = e.x * 32.0f + p.x; o.y = e.y * 32.0f + p.y;
  o.z = e.z * 32.0f + p.z; o.w = e.w * 32.0f + p.w;
  ((float4*)(out + (long)row * DD))[i] = o;
}

// ---------------------------------------------------------------------------
// LayerNorm(a [+ res]) -> yf (f32, optional) and yb (bf16). One block per row.
// ---------------------------------------------------------------------------
__global__ __launch_bounds__(256) void ln_kernel(
    const float* __restrict__ a, const float* __restrict__ res,
    float* __restrict__ yf, u16* __restrict__ yb)
{
  const int row = blockIdx.x;
  const int i = threadIdx.x;
  const int lane = i & 63, wid = i >> 6;
  float4 x = ((const float4*)(a + (long)row * DD))[i];
  if (res){
    float4 r4 = ((const float4*)(res + (long)row * DD))[i];
    x.x += r4.x; x.y += r4.y; x.z += r4.z; x.w += r4.w;
  }
  float s = x.x + x.y + x.z + x.w;
  #pragma unroll
  for (int o = 32; o; o >>= 1) s += __shfl_xor(s, o);
  __shared__ float red[4];
  if (lane == 0) red[wid] = s;
  __syncthreads();
  const float mean = (red[0] + red[1] + red[2] + red[3]) * (1.0f / DD);
  __syncthreads();
  const float dx = x.x - mean, dy = x.y - mean, dz = x.z - mean, dw = x.w - mean;
  float q = dx*dx + dy*dy + dz*dz + dw*dw;
  #pragma unroll
  for (int o = 32; o; o >>= 1) q += __shfl_xor(q, o);
  if (lane == 0) red[wid] = q;
  __syncthreads();
  const float var = (red[0] + red[1] + red[2] + red[3]) * (1.0f / DD);
  const float rstd = rsqrtf(var + 1e-5f);
  float4 y; y.x = dx*rstd; y.y = dy*rstd; y.z = dz*rstd; y.w = dw*rstd;
  if (yf) ((float4*)(yf + (long)row * DD))[i] = y;
  ushort4 o4; o4.x = f2bf(y.x); o4.y = f2bf(y.y); o4.z = f2bf(y.z); o4.w = f2bf(y.w);
  ((ushort4*)(yb + (long)row * DD))[i] = o4;
}

// ---------------------------------------------------------------------------
// Masked softmax, in-place on bf16 scores [B*H*T rows of S=512].
// ---------------------------------------------------------------------------
__global__ __launch_bounds__(256) void softmax_kernel(
    u16* __restrict__ P, const int* __restrict__ cmask, int mode)
{
  const long rid = (long)blockIdx.x * 4 + (threadIdx.x >> 6);
  const int lane = threadIdx.x & 63;
  const int t = (int)(rid & (TT - 1));
  const int b = (int)(rid >> 13);          // rid / (H*T)
  u16* row = P + rid * TT;
  union { int4 v; u16 u[8]; } U;
  U.v = ((const int4*)row)[lane];
  const int sbase = lane * 8;
  float p[8];
  float m = -3e38f;
  #pragma unroll
  for (int j = 0; j < 8; ++j){
    float v = bf2f(U.u[j]);
    bool ok = (mode < 0) ? (sbase + j <= t)
                         : (cmask[b * TT + sbase + j] != mode);
    v = ok ? v : -1e20f;
    p[j] = v;
    m = fmaxf(m, v);
  }
  #pragma unroll
  for (int o = 32; o; o >>= 1) m = fmaxf(m, __shfl_xor(m, o));
  float s = 0.0f;
  #pragma unroll
  for (int j = 0; j < 8; ++j){ p[j] = __expf(p[j] - m); s += p[j]; }
  #pragma unroll
  for (int o = 32; o; o >>= 1) s += __shfl_xor(s, o);
  const float inv = 1.0f / s;
  #pragma unroll
  for (int j = 0; j < 8; ++j) U.u[j] = f2bf(p[j] * inv);
  ((int4*)row)[lane] = U.v;
}

// ---------------------------------------------------------------------------
// m97-structure bf16 MFMA GEMM: C = alpha*(A·B^T + bias)
//   A [M][K] (lda), B [N][K] (ldb) bf16; global_load_lds w16 staging;
//   linear LDS [rows][32] bf16 with XOR chunk swizzle (2-way reads = free).
// Batch: A += z*zsA; B += (z/zdivB)*zsB1 + (z%zdivB)*zsB2;
//        cbase = (z/zdivC)*czs1 + (z%zdivC)*czs2.
// MODE 0 plain f32 (Cf); 1 plain bf16 (Cb0); 3 self-QKV fused (N=3072;
// Q scaled by alpha -> Cb0 [b,h,t,d]; K -> Cb1 [b,h,t,d]; V -> Cb2 [b,h,d,s]);
// 4 cross-KV (z&1 ? V-layout : K-layout, bias sel by z&1, + (z>>1)*bzs);
// 5 Q-layout single output with alpha.
// ---------------------------------------------------------------------------
#define MODE_F32  0
#define MODE_BF16 1
#define MODE_QKV  3
#define MODE_KV   4
#define MODE_Q    5

__device__ __forceinline__ long qk_off(int gm, int gn){   // [b,h,t,d]
  return (((long)(gm >> 9) * HH + (gn >> 6)) * TT + (gm & (TT-1))) * DHH + (gn & (DHH-1));
}
__device__ __forceinline__ long vt_off(int gm, int gn){   // [b,h,d,s]
  return (((long)(gm >> 9) * HH + (gn >> 6)) * DHH + (gn & (DHH-1))) * TT + (gm & (TT-1));
}

template<int BM, int BN, int MODE>
__global__ __launch_bounds__(256) void gemm_k(
    const u16* __restrict__ A, const u16* __restrict__ B,
    const float* __restrict__ bias0, const float* __restrict__ bias1,
    const float* __restrict__ bias2,
    float* __restrict__ Cf, u16* __restrict__ Cb0,
    u16* __restrict__ Cb1, u16* __restrict__ Cb2,
    int K, int lda, int ldb, int ldc,
    long zsA, long zsB1, long zsB2, int zdivB,
    long czs1, long czs2, int zdivC, long bzs,
    int relu, float alpha)
{
  constexpr int BK = 32;
  __shared__ __align__(16) u16 As[BM * BK];
  __shared__ __align__(16) u16 Bs[BN * BK];
  const int z = blockIdx.z;
  const u16* Ab = A + (long)z * zsA;
  const u16* Bb = B + (long)(z / zdivB) * zsB1 + (long)(z % zdivB) * zsB2;
  const long cbase = (long)(z / zdivC) * czs1 + (long)(z % zdivC) * czs2;
  const int tid = threadIdx.x, lane = tid & 63, wid = tid >> 6;
  const int m0 = blockIdx.y * BM, n0 = blockIdx.x * BN;
  constexpr int WGN = (BN >= 128) ? 2 : 1, WGM = 4 / WGN;
  constexpr int TMW = BM / WGM, TNW = BN / WGN;
  constexpr int FM = TMW / 16, FN = TNW / 16;
  const int wm = (wid / WGN) * TMW, wn = (wid % WGN) * TNW;
  const int fr = lane & 15, kg = lane >> 4;
  facc4 acc[FM][FN] = {};
  // staging map: thread t -> row (t>>2) [per 64-row pass], 16B chunk (t&3).
  // global chunk pre-swizzled so LDS[r][c] = global[r][c ^ ((r>>1)&3)]
  const int srow = tid >> 2;
  const int gcol = (((tid & 3) ^ ((srow >> 1) & 3)) * 8);
  constexpr int AP = (BM * 64) / 4096, BP = (BN * 64) / 4096;
  u16* Aw = As + wid * 512;   // wave-uniform LDS base (u16 units), +p*2048
  u16* Bw = Bs + wid * 512;
  const int rsw = (kg ^ ((fr >> 1) & 3)) * 8;   // read-side swizzled k-chunk

  for (int k0 = 0; k0 < K; k0 += BK){
    #pragma unroll
    for (int p = 0; p < AP; ++p)
      gload16(Ab + (long)(m0 + p*64 + srow) * lda + (k0 + gcol), Aw + p*2048);
    #pragma unroll
    for (int p = 0; p < BP; ++p)
      gload16(Bb + (long)(n0 + p*64 + srow) * ldb + (k0 + gcol), Bw + p*2048);
    __syncthreads();                       // drains vmcnt -> tile visible
    bfrag8 af[FM], bfr[FN];
    #pragma unroll
    for (int i = 0; i < FM; ++i)
      af[i] = *(const bfrag8*)&As[(wm + i*16 + fr) * 32 + rsw];
    #pragma unroll
    for (int j = 0; j < FN; ++j)
      bfr[j] = *(const bfrag8*)&Bs[(wn + j*16 + fr) * 32 + rsw];
    #pragma unroll
    for (int i = 0; i < FM; ++i)
      #pragma unroll
      for (int j = 0; j < FN; ++j)
        acc[i][j] = __builtin_amdgcn_mfma_f32_16x16x32_bf16(af[i], bfr[j], acc[i][j], 0, 0, 0);
    __syncthreads();                       // LDS reads done before next stage
  }

  // Epilogue. C/D frag layout: col = fr, row = kg*4 + rr.
  #pragma unroll
  for (int i = 0; i < FM; ++i){
    #pragma unroll
    for (int j = 0; j < FN; ++j){
      const int gn = n0 + wn + j*16 + fr;
      #pragma unroll
      for (int rr = 0; rr < 4; ++rr){
        const int gm = m0 + wm + i*16 + kg*4 + rr;
        float v = acc[i][j][rr];
        if constexpr (MODE == MODE_F32){
          v = (v + (bias0 ? bias0[gn] : 0.0f)) * alpha;
          if (relu) v = fmaxf(v, 0.0f);
          Cf[cbase + (long)gm * ldc + gn] = v;
        } else if constexpr (MODE == MODE_BF16){
          v = (v + (bias0 ? bias0[gn] : 0.0f)) * alpha;
          if (relu) v = fmaxf(v, 0.0f);
          Cb0[cbase + (long)gm * ldc + gn] = f2bf(v);
        } else if constexpr (MODE == MODE_QKV){
          const int sect = gn >> 10, nn = gn & (DD - 1);
          if (sect == 0)      Cb0[qk_off(gm, nn)] = f2bf((v + bias0[nn]) * alpha);
          else if (sect == 1) Cb1[qk_off(gm, nn)] = f2bf(v + bias1[nn]);
          else                Cb2[vt_off(gm, nn)] = f2bf(v + bias2[nn]);
        } else if constexpr (MODE == MODE_Q){
          Cb0[qk_off(gm, gn)] = f2bf((v + bias0[gn]) * alpha);
        } else {  // MODE_KV
          const float* bp = ((z & 1) ? bias1 : bias0) + (long)(z >> 1) * bzs;
          const float vb = v + bp[gn];
          if (z & 1) Cb0[cbase + vt_off(gm, gn)] = f2bf(vb);
          else       Cb0[cbase + qk_off(gm, gn)] = f2bf(vb);
        }
      }
    }
  }
}

// ---------------------------------------------------------------------------
extern "C" void kernel_launch(void* const* d_in, const int* in_sizes, int n_in,
                              void* d_out, int out_size, void* d_ws, size_t ws_size,
                              hipStream_t stream)
{
  (void)in_sizes; (void)n_in; (void)out_size; (void)ws_size;
  const float* emb   = (const float*)d_in[0];
  const int*   pvec  = (const int*)d_in[1];
  const float* g_enc = (const float*)d_in[2];
  const float* g_con = (const float*)d_in[3];
  const float* g_db  = (const float*)d_in[4];
  const float* g_usr = (const float*)d_in[5];
  const int*   cmask = (const int*)d_in[6];
  const float* pose  = (const float*)d_in[7];
  const float* Wq = (const float*)d_in[8];
  const float* bq = (const float*)d_in[9];
  const float* Wk = (const float*)d_in[10];
  const float* bk = (const float*)d_in[11];
  const float* Wv = (const float*)d_in[12];
  const float* bv = (const float*)d_in[13];
  const float* Wo = (const float*)d_in[14];
  const float* bo = (const float*)d_in[15];
  const float* W1 = (const float*)d_in[16];
  const float* b1 = (const float*)d_in[17];
  const float* W2 = (const float*)d_in[18];
  const float* b2 = (const float*)d_in[19];
  float* out = (float*)d_out;

  const size_t NTOK = (size_t)BB * TT;   // 2048
  const long D2 = (long)DD * DD;

  char* wp = (char*)d_ws;
  auto alloc = [&](size_t bytes) -> char* {
    char* p = wp;
    wp += (bytes + 255) & ~(size_t)255;
    return p;
  };
  u16*   WqkvS = (u16*)  alloc(sizeof(u16) * 2 * 3 * D2);        // [l][q,k,v][D][D]
  u16*   WkvC  = (u16*)  alloc(sizeof(u16) * 2 * 4 * 2 * D2);    // [l][ci][k,v][D][D]
  u16*   WqC   = (u16*)  alloc(sizeof(u16) * 2 * 4 * D2);        // [l][ci][D][D]
  u16*   WoT   = (u16*)  alloc(sizeof(u16) * 10 * D2);           // [l*5+i][D][D]
  u16*   W1T   = (u16*)  alloc(sizeof(u16) * 2 * DD * FF);
  u16*   W2T   = (u16*)  alloc(sizeof(u16) * 2 * DD * FF);
  u16*   kvb0  = (u16*)  alloc(sizeof(u16) * NTOK * DD);   // db      (i=1)
  u16*   kvb1  = (u16*)  alloc(sizeof(u16) * NTOK * DD);   // concept (i=2)
  u16*   kvb2  = (u16*)  alloc(sizeof(u16) * NTOK * DD);   // user    (i=3)
  u16*   kvb3  = (u16*)  alloc(sizeof(u16) * NTOK * DD);   // encoder (i=4)
  u16*   KVc   = (u16*)  alloc(sizeof(u16) * 16 * NTOK * DD);  // [l][ci][k,v] blocks
  float* xf    = (float*)alloc(sizeof(float) * NTOK * DD);
  u16*   xb    = (u16*)  alloc(sizeof(u16) * NTOK * DD);
  u16*   Qb    = (u16*)  alloc(sizeof(u16) * NTOK * DD);
  u16*   Kb    = (u16*)  alloc(sizeof(u16) * NTOK * DD);
  u16*   Vtb   = (u16*)  alloc(sizeof(u16) * NTOK * DD);
  u16*   scr   = (u16*)  alloc(sizeof(u16) * (size_t)BB * HH * TT * TT);
  u16*   attnb = (u16*)  alloc(sizeof(u16) * NTOK * DD);
  float* obuf  = (float*)alloc(sizeof(float) * NTOK * DD);
  u16*   hb    = (u16*)  alloc(sizeof(u16) * NTOK * FF);

  // ---- weight prep (9 transpose launches) ----
  const dim3 tg(32, 32, 2);
  transpose_w_kernel<<<tg, 256, 0, stream>>>(Wq, WqkvS,          DD, DD, 5*D2, 0, 3*D2, 0, 1);
  transpose_w_kernel<<<tg, 256, 0, stream>>>(Wk, WqkvS + D2,     DD, DD, 5*D2, 0, 3*D2, 0, 1);
  transpose_w_kernel<<<tg, 256, 0, stream>>>(Wv, WqkvS + 2*D2,   DD, DD, 5*D2, 0, 3*D2, 0, 1);
  transpose_w_kernel<<<dim3(32,32,8), 256, 0, stream>>>(Wk + D2, WkvC,      DD, DD, 5*D2, D2, 8*D2, 2*D2, 4);
  transpose_w_kernel<<<dim3(32,32,8), 256, 0, stream>>>(Wv + D2, WkvC + D2, DD, DD, 5*D2, D2, 8*D2, 2*D2, 4);
  transpose_w_kernel<<<dim3(32,32,8), 256, 0, stream>>>(Wq + D2, WqC,       DD, DD, 5*D2, D2, 4*D2, D2,   4);
  transpose_w_kernel<<<dim3(32,32,10),256, 0, stream>>>(Wo, WoT,            DD, DD, D2, 0, D2, 0, 1);
  transpose_w_kernel<<<dim3(128,32,2),256, 0, stream>>>(W1, W1T, DD, FF, (long)DD*FF, 0, (long)DD*FF, 0, 1);
  transpose_w_kernel<<<dim3(32,128,2),256, 0, stream>>>(W2, W2T, FF, DD, (long)DD*FF, 0, (long)DD*FF, 0, 1);

  // ---- kv inputs f32 -> bf16 (one launch) ----
  const int n4 = (int)(NTOK * DD / 4);
  f32_to_bf16_4<<<dim3(n4/256, 4, 1), 256, 0, stream>>>(
      g_db, g_con, g_usr, g_enc, kvb0, kvb1, kvb2, kvb3, n4);

  // ---- embedding + initial LN ----
  embed_kernel<<<(int)NTOK, 256, 0, stream>>>(emb, pvec, pose, obuf);
  ln_kernel<<<(int)NTOK, 256, 0, stream>>>(obuf, nullptr, xf, xb);

  // ---- precompute all cross-attention K/V (constant inputs), 4 launches ----
  const u16* kvPtr[4] = {kvb0, kvb1, kvb2, kvb3};
  const long NB = (long)NTOK * DD;               // one K or V block
  for (int ci = 0; ci < 4; ++ci){
    gemm_k<128,128,MODE_KV><<<dim3(8,16,4), 256, 0, stream>>>(
      kvPtr[ci], WkvC + (long)ci*2*D2,
      bk + (ci+1)*DD, bv + (ci+1)*DD, nullptr,
      nullptr, KVc + (long)ci*2*NB, nullptr, nullptr,
      DD, DD, DD, 0,
      0, 8*D2, D2, 2,
      8*NB, NB, 2, 5*DD,
      0, 1.0f);
  }

  const int modeTab[5] = {-1, 2, 1, 3, 0};   // causal, !=DB, !=CONCEPT, !=USER, !=PAD

  for (int l = 0; l < 2; ++l){
    for (int i = 0; i < 5; ++i){
      const u16 *Kp, *Vp;
      if (i == 0){
        // fused self Q/K/V: N = 3072
        gemm_k<64,128,MODE_QKV><<<dim3(24,32,1), 256, 0, stream>>>(
          xb, WqkvS + (long)l*3*D2,
          bq + (size_t)l*5*DD, bk + (size_t)l*5*DD, bv + (size_t)l*5*DD,
          nullptr, Qb, Kb, Vtb,
          DD, DD, DD, 0,
          0, 0, 0, 1, 0, 0, 1, 0,
          0, 0.125f);
        Kp = Kb; Vp = Vtb;
      } else {
        const int ci = i - 1;
        gemm_k<64,128,MODE_Q><<<dim3(8,32,1), 256, 0, stream>>>(
          xb, WqC + (long)(l*4 + ci)*D2,
          bq + (size_t)(l*5 + i)*DD, nullptr, nullptr,
          nullptr, Qb, nullptr, nullptr,
          DD, DD, DD, 0,
          0, 0, 0, 1, 0, 0, 1, 0,
          0, 0.125f);
        Kp = KVc + ((long)l*4 + ci)*2*NB;
        Vp = Kp + NB;
      }
      // scores = Q @ K^T (batched over b*h)
      gemm_k<128,128,MODE_BF16><<<dim3(4,4,64), 256, 0, stream>>>(
        Qb, Kp, nullptr, nullptr, nullptr,
        nullptr, scr, nullptr, nullptr,
        DHH, DHH, DHH, TT,
        (long)TT*DHH, (long)TT*DHH, 0, 1,
        (long)TT*TT, 0, 1, 0,
        0, 1.0f);
      softmax_kernel<<<BB*HH*TT/4, 256, 0, stream>>>(scr, cmask, modeTab[i]);
      // attn = P @ V -> [B*T][D]
      gemm_k<128,64,MODE_BF16><<<dim3(1,4,64), 256, 0, stream>>>(
        scr, Vp, nullptr, nullptr, nullptr,
        nullptr, attnb, nullptr, nullptr,
        TT, TT, TT, DD,
        (long)TT*TT, (long)DHH*TT, 0, 1,
        (long)TT*DD, DHH, 16, 0,
        0, 1.0f);
      // O-projection (f32 out for residual)
      gemm_k<64,128,MODE_F32><<<dim3(8,32,1), 256, 0, stream>>>(
        attnb, WoT + (long)(l*5 + i)*D2,
        bo + (size_t)(l*5 + i)*DD, nullptr, nullptr,
        obuf, nullptr, nullptr, nullptr,
        DD, DD, DD, DD,
        0, 0, 0, 1, 0, 0, 1, 0,
        0, 1.0f);
      ln_kernel<<<(int)NTOK, 256, 0, stream>>>(obuf, xf, xf, xb);
    }
    // FFN
    gemm_k<128,128,MODE_BF16><<<dim3(32,16,1), 256, 0, stream>>>(
      xb, W1T + (size_t)l*DD*FF,
      b1 + (size_t)l*FF, nullptr, nullptr,
      nullptr, hb, nullptr, nullptr,
      DD, DD, DD, FF,
      0, 0, 0, 1, 0, 0, 1, 0,
      1, 1.0f);
    gemm_k<64,128,MODE_F32><<<dim3(8,32,1), 256, 0, stream>>>(
      hb, W2T + (size_t)l*DD*FF,
      b2 + (size_t)l*DD, nullptr, nullptr,
      obuf, nullptr, nullptr, nullptr,
      FF, FF, FF, DD,
      0, 0, 0, 1, 0, 0, 1, 0,
      0, 1.0f);
    float* yf = (l == 1) ? out : xf;
    ln_kernel<<<(int)NTOK, 256, 0, stream>>>(obuf, xf, yf, xb);
  }
}

// Round 3
// 1698.668 us; speedup vs baseline: 2.3943x; 1.1128x over previous
//
#include <hip/hip_runtime.h>

// Problem constants (Bert4KGModel): B=4, T=S=512, D=1024, H=16, dh=64, F=4096, L=2
#define BB  4
#define TT  512
#define DD  1024
#define HH  16
#define DHH 64
#define FF  4096

typedef unsigned short u16;
typedef __attribute__((ext_vector_type(8))) short bfrag8;   // 8 bf16 (4 VGPRs)
typedef __attribute__((ext_vector_type(4))) float facc4;    // 4 f32 acc

__device__ __forceinline__ u16 f2bf(float f){
  unsigned u = __float_as_uint(f);
  unsigned r = u + 0x7fffu + ((u >> 16) & 1u);   // RNE
  return (u16)(r >> 16);
}
__device__ __forceinline__ float bf2f(u16 h){
  return __uint_as_float(((unsigned)h) << 16);
}

// async global->LDS, 16B per lane; LDS dest is wave-uniform base + lane*16
__device__ __forceinline__ void gload16(const u16* g, u16* l){
  __builtin_amdgcn_global_load_lds(
      (const __attribute__((address_space(1))) void*)g,
      (__attribute__((address_space(3))) void*)l, 16, 0, 0);
}

// ---------------------------------------------------------------------------
// Weight transpose + f32->bf16 with generalized z-mapping
// ---------------------------------------------------------------------------
__global__ __launch_bounds__(256) void transpose_w_kernel(
    const float* __restrict__ W, u16* __restrict__ Wt, int R, int C,
    long szs1, long szs2, long dzs1, long dzs2, int zdiv)
{
  __shared__ float tile[32][33];
  const int tx = threadIdx.x & 31, ty = threadIdx.x >> 5;   // 32 x 8
  const int z = blockIdx.z;
  const long so = (long)(z / zdiv) * szs1 + (long)(z % zdiv) * szs2;
  const long dzo = (long)(z / zdiv) * dzs1 + (long)(z % zdiv) * dzs2;
  const int c0 = blockIdx.x << 5, r0 = blockIdx.y << 5;
  #pragma unroll
  for (int i = 0; i < 4; ++i)
    tile[ty + i*8][tx] = W[so + (long)(r0 + ty + i*8)*C + c0 + tx];
  __syncthreads();
  #pragma unroll
  for (int i = 0; i < 4; ++i)
    Wt[dzo + (long)(c0 + ty + i*8)*R + r0 + tx] = f2bf(tile[tx][ty + i*8]);
}

// ---------------------------------------------------------------------------
// 4 buffers f32 -> bf16 in one launch
// ---------------------------------------------------------------------------
__global__ __launch_bounds__(256) void f32_to_bf16_4(
    const float* __restrict__ a0, const float* __restrict__ a1,
    const float* __restrict__ a2, const float* __restrict__ a3,
    u16* __restrict__ o0, u16* __restrict__ o1,
    u16* __restrict__ o2, u16* __restrict__ o3, int n4)
{
  const float* s; u16* d;
  switch (blockIdx.y){
    case 0: s = a0; d = o0; break;
    case 1: s = a1; d = o1; break;
    case 2: s = a2; d = o2; break;
    default: s = a3; d = o3; break;
  }
  int i = blockIdx.x * 256 + threadIdx.x;
  if (i >= n4) return;
  float4 v = ((const float4*)s)[i];
  ushort4 o;
  o.x = f2bf(v.x); o.y = f2bf(v.y); o.z = f2bf(v.z); o.w = f2bf(v.w);
  ((ushort4*)d)[i] = o;
}

// ---------------------------------------------------------------------------
// Embedding gather
// ---------------------------------------------------------------------------
__global__ __launch_bounds__(256) void embed_kernel(
    const float* __restrict__ emb, const int* __restrict__ pvec,
    const float* __restrict__ pos, float* __restrict__ out)
{
  const int row = blockIdx.x;
  const int i = threadIdx.x;
  const int idx = pvec[row];
  const int t = row & (TT - 1);
  float4 e = ((const float4*)(emb + (long)idx * DD))[i];
  float4 p = ((const float4*)(pos + (long)t * DD))[i];
  float4 o;
  o.x = e.x * 32.0f + p.x; o.y = e.y * 32.0f + p.y;
  o.z = e.z * 32.0f + p.z; o.w = e.w * 32.0f + p.w;
  ((float4*)(out + (long)row * DD))[i] = o;
}

// ---------------------------------------------------------------------------
// LayerNorm(a [+ res]) -> yf (f32, optional) and yb (bf16)
// ---------------------------------------------------------------------------
__global__ __launch_bounds__(256) void ln_kernel(
    const float* __restrict__ a, const float* __restrict__ res,
    float* __restrict__ yf, u16* __restrict__ yb)
{
  const int row = blockIdx.x;
  const int i = threadIdx.x;
  const int lane = i & 63, wid = i >> 6;
  float4 x = ((const float4*)(a + (long)row * DD))[i];
  if (res){
    float4 r4 = ((const float4*)(res + (long)row * DD))[i];
    x.x += r4.x; x.y += r4.y; x.z += r4.z; x.w += r4.w;
  }
  float s = x.x + x.y + x.z + x.w;
  #pragma unroll
  for (int o = 32; o; o >>= 1) s += __shfl_xor(s, o);
  __shared__ float red[4];
  if (lane == 0) red[wid] = s;
  __syncthreads();
  const float mean = (red[0] + red[1] + red[2] + red[3]) * (1.0f / DD);
  __syncthreads();
  const float dx = x.x - mean, dy = x.y - mean, dz = x.z - mean, dw = x.w - mean;
  float q = dx*dx + dy*dy + dz*dz + dw*dw;
  #pragma unroll
  for (int o = 32; o; o >>= 1) q += __shfl_xor(q, o);
  if (lane == 0) red[wid] = q;
  __syncthreads();
  const float var = (red[0] + red[1] + red[2] + red[3]) * (1.0f / DD);
  const float rstd = rsqrtf(var + 1e-5f);
  float4 y; y.x = dx*rstd; y.y = dy*rstd; y.z = dz*rstd; y.w = dw*rstd;
  if (yf) ((float4*)(yf + (long)row * DD))[i] = y;
  ushort4 o4; o4.x = f2bf(y.x); o4.y = f2bf(y.y); o4.z = f2bf(y.z); o4.w = f2bf(y.w);
  ((ushort4*)(yb + (long)row * DD))[i] = o4;
}

// ---------------------------------------------------------------------------
// Masked softmax, in-place on bf16 scores [B*H*T rows of S=512].
// ---------------------------------------------------------------------------
__global__ __launch_bounds__(256) void softmax_kernel(
    u16* __restrict__ P, const int* __restrict__ cmask, int mode)
{
  const long rid = (long)blockIdx.x * 4 + (threadIdx.x >> 6);
  const int lane = threadIdx.x & 63;
  const int t = (int)(rid & (TT - 1));
  const int b = (int)(rid >> 13);
  u16* row = P + rid * TT;
  union { int4 v; u16 u[8]; } U;
  U.v = ((const int4*)row)[lane];
  const int sbase = lane * 8;
  float p[8];
  float m = -3e38f;
  #pragma unroll
  for (int j = 0; j < 8; ++j){
    float v = bf2f(U.u[j]);
    bool ok = (mode < 0) ? (sbase + j <= t)
                         : (cmask[b * TT + sbase + j] != mode);
    v = ok ? v : -1e20f;
    p[j] = v;
    m = fmaxf(m, v);
  }
  #pragma unroll
  for (int o = 32; o; o >>= 1) m = fmaxf(m, __shfl_xor(m, o));
  float s = 0.0f;
  #pragma unroll
  for (int j = 0; j < 8; ++j){ p[j] = __expf(p[j] - m); s += p[j]; }
  #pragma unroll
  for (int o = 32; o; o >>= 1) s += __shfl_xor(s, o);
  const float inv = 1.0f / s;
  #pragma unroll
  for (int j = 0; j < 8; ++j) U.u[j] = f2bf(p[j] * inv);
  ((int4*)row)[lane] = U.v;
}

// ---------------------------------------------------------------------------
// bf16 MFMA GEMM, BK=64, double-buffered LDS pipeline (2-phase), XCD swizzle.
//   C = alpha*(A·B^T + bias);  A [M][K] (lda), B [N][K] (ldb) bf16.
// LDS layout: [rows][64] u16, 16B-chunk XOR swizzle  phys = c ^ (row&7);
// stage via global_load_lds w16 with pre-swizzled global source.
// Batch/output modes identical to round 2.
// ---------------------------------------------------------------------------
#define MODE_F32  0
#define MODE_BF16 1
#define MODE_QKV  3
#define MODE_KV   4
#define MODE_Q    5

__device__ __forceinline__ long qk_off(int gm, int gn){   // [b,h,t,d]
  return (((long)(gm >> 9) * HH + (gn >> 6)) * TT + (gm & (TT-1))) * DHH + (gn & (DHH-1));
}
__device__ __forceinline__ long vt_off(int gm, int gn){   // [b,h,d,s]
  return (((long)(gm >> 9) * HH + (gn >> 6)) * DHH + (gn & (DHH-1))) * TT + (gm & (TT-1));
}

template<int BM, int BN, int MODE>
__global__ __launch_bounds__(256, 2) void gemm_k(
    const u16* __restrict__ A, const u16* __restrict__ B,
    const float* __restrict__ bias0, const float* __restrict__ bias1,
    const float* __restrict__ bias2,
    float* __restrict__ Cf, u16* __restrict__ Cb0,
    u16* __restrict__ Cb1, u16* __restrict__ Cb2,
    int K, int lda, int ldb, int ldc,
    long zsA, long zsB1, long zsB2, int zdivB,
    long czs1, long czs2, int zdivC, long bzs,
    int relu, float alpha)
{
  constexpr int BK = 64;
  constexpr int ASZ = BM * BK, BSZ = BN * BK;           // u16 per buffer
  __shared__ __align__(16) u16 As[2 * ASZ];
  __shared__ __align__(16) u16 Bs[2 * BSZ];

  // ---- XCD-aware bijective block swizzle (all grids are %8 == 0) ----
  const int gx = gridDim.x, gy = gridDim.y;
  const int nwg = gx * gy * gridDim.z;
  const int fid = (blockIdx.z * gy + blockIdx.y) * gx + blockIdx.x;
  const int cpx = nwg >> 3;
  const int lid = (fid & 7) * cpx + (fid >> 3);
  const int bx = lid % gx;
  const int rem = lid / gx;
  const int by = rem % gy;
  const int z  = rem / gy;

  const u16* Ab = A + (long)z * zsA;
  const u16* Bb = B + (long)(z / zdivB) * zsB1 + (long)(z % zdivB) * zsB2;
  const long cbase = (long)(z / zdivC) * czs1 + (long)(z % zdivC) * czs2;
  const int tid = threadIdx.x, lane = tid & 63, wid = tid >> 6;
  const int m0 = by * BM, n0 = bx * BN;
  constexpr int WGN = (BN >= 128) ? 2 : 1, WGM = 4 / WGN;
  constexpr int TMW = BM / WGM, TNW = BN / WGN;
  constexpr int FM = TMW / 16, FN = TNW / 16;
  const int wm = (wid / WGN) * TMW, wn = (wid % WGN) * TNW;
  const int fr = lane & 15, kg = lane >> 4;
  facc4 acc[FM][FN] = {};

  // staging: pass = 32 rows (4KB); thread t -> row t>>3, phys chunk t&7;
  // global chunk pre-swizzled: g = (t&7) ^ ((t>>3)&7)
  const int srow = tid >> 3;                       // 0..31 within pass
  const int gcol = (((tid & 7) ^ (srow & 7)) * 8); // u16 offset in row
  constexpr int AP = BM / 32, BP = BN / 32;

  auto stage = [&](int buf, int k0){
    u16* Ad = As + buf * ASZ + wid * 512;
    u16* Bd = Bs + buf * BSZ + wid * 512;
    #pragma unroll
    for (int p = 0; p < AP; ++p)
      gload16(Ab + (long)(m0 + p*32 + srow) * lda + (k0 + gcol), Ad + p*2048);
    #pragma unroll
    for (int p = 0; p < BP; ++p)
      gload16(Bb + (long)(n0 + p*32 + srow) * ldb + (k0 + gcol), Bd + p*2048);
  };

  const int nsteps = K / BK;
  stage(0, 0);
  __syncthreads();                                  // drains vmcnt -> buf0 ready

  for (int s = 0; s < nsteps; ++s){
    const int cur = s & 1;
    if (s + 1 < nsteps) stage(cur ^ 1, (s + 1) * BK);
    const u16* Ar = As + cur * ASZ;
    const u16* Br = Bs + cur * BSZ;
    bfrag8 af[FM][2], bfv[FN][2];
    #pragma unroll
    for (int i = 0; i < FM; ++i)
      #pragma unroll
      for (int s2 = 0; s2 < 2; ++s2)
        af[i][s2] = *(const bfrag8*)&Ar[(wm + i*16 + fr) * 64 + (((s2*4 + kg) ^ (fr & 7)) * 8)];
    #pragma unroll
    for (int j = 0; j < FN; ++j)
      #pragma unroll
      for (int s2 = 0; s2 < 2; ++s2)
        bfv[j][s2] = *(const bfrag8*)&Br[(wn + j*16 + fr) * 64 + (((s2*4 + kg) ^ (fr & 7)) * 8)];
    #pragma unroll
    for (int i = 0; i < FM; ++i)
      #pragma unroll
      for (int j = 0; j < FN; ++j){
        acc[i][j] = __builtin_amdgcn_mfma_f32_16x16x32_bf16(af[i][0], bfv[j][0], acc[i][j], 0, 0, 0);
        acc[i][j] = __builtin_amdgcn_mfma_f32_16x16x32_bf16(af[i][1], bfv[j][1], acc[i][j], 0, 0, 0);
      }
    if (s + 1 < nsteps) __syncthreads();   // drain prefetch + release buf[cur]
  }

  // Epilogue. C/D frag layout: col = fr, row = kg*4 + rr.
  #pragma unroll
  for (int i = 0; i < FM; ++i){
    #pragma unroll
    for (int j = 0; j < FN; ++j){
      const int gn = n0 + wn + j*16 + fr;
      #pragma unroll
      for (int rr = 0; rr < 4; ++rr){
        const int gm = m0 + wm + i*16 + kg*4 + rr;
        float v = acc[i][j][rr];
        if constexpr (MODE == MODE_F32){
          v = (v + (bias0 ? bias0[gn] : 0.0f)) * alpha;
          if (relu) v = fmaxf(v, 0.0f);
          Cf[cbase + (long)gm * ldc + gn] = v;
        } else if constexpr (MODE == MODE_BF16){
          v = (v + (bias0 ? bias0[gn] : 0.0f)) * alpha;
          if (relu) v = fmaxf(v, 0.0f);
          Cb0[cbase + (long)gm * ldc + gn] = f2bf(v);
        } else if constexpr (MODE == MODE_QKV){
          const int sect = gn >> 10, nn = gn & (DD - 1);
          if (sect == 0)      Cb0[qk_off(gm, nn)] = f2bf((v + bias0[nn]) * alpha);
          else if (sect == 1) Cb1[qk_off(gm, nn)] = f2bf(v + bias1[nn]);
          else                Cb2[vt_off(gm, nn)] = f2bf(v + bias2[nn]);
        } else if constexpr (MODE == MODE_Q){
          Cb0[qk_off(gm, gn)] = f2bf((v + bias0[gn]) * alpha);
        } else {  // MODE_KV
          const float* bp = ((z & 1) ? bias1 : bias0) + (long)(z >> 1) * bzs;
          const float vb = v + bp[gn];
          if (z & 1) Cb0[cbase + vt_off(gm, gn)] = f2bf(vb);
          else       Cb0[cbase + qk_off(gm, gn)] = f2bf(vb);
        }
      }
    }
  }
}

// ---------------------------------------------------------------------------
extern "C" void kernel_launch(void* const* d_in, const int* in_sizes, int n_in,
                              void* d_out, int out_size, void* d_ws, size_t ws_size,
                              hipStream_t stream)
{
  (void)in_sizes; (void)n_in; (void)out_size; (void)ws_size;
  const float* emb   = (const float*)d_in[0];
  const int*   pvec  = (const int*)d_in[1];
  const float* g_enc = (const float*)d_in[2];
  const float* g_con = (const float*)d_in[3];
  const float* g_db  = (const float*)d_in[4];
  const float* g_usr = (const float*)d_in[5];
  const int*   cmask = (const int*)d_in[6];
  const float* pose  = (const float*)d_in[7];
  const float* Wq = (const float*)d_in[8];
  const float* bq = (const float*)d_in[9];
  const float* Wk = (const float*)d_in[10];
  const float* bk = (const float*)d_in[11];
  const float* Wv = (const float*)d_in[12];
  const float* bv = (const float*)d_in[13];
  const float* Wo = (const float*)d_in[14];
  const float* bo = (const float*)d_in[15];
  const float* W1 = (const float*)d_in[16];
  const float* b1 = (const float*)d_in[17];
  const float* W2 = (const float*)d_in[18];
  const float* b2 = (const float*)d_in[19];
  float* out = (float*)d_out;

  const size_t NTOK = (size_t)BB * TT;   // 2048
  const long D2 = (long)DD * DD;

  char* wp = (char*)d_ws;
  auto alloc = [&](size_t bytes) -> char* {
    char* p = wp;
    wp += (bytes + 255) & ~(size_t)255;
    return p;
  };
  u16*   WqkvS = (u16*)  alloc(sizeof(u16) * 2 * 3 * D2);
  u16*   WkvC  = (u16*)  alloc(sizeof(u16) * 2 * 4 * 2 * D2);
  u16*   WqC   = (u16*)  alloc(sizeof(u16) * 2 * 4 * D2);
  u16*   WoT   = (u16*)  alloc(sizeof(u16) * 10 * D2);
  u16*   W1T   = (u16*)  alloc(sizeof(u16) * 2 * DD * FF);
  u16*   W2T   = (u16*)  alloc(sizeof(u16) * 2 * DD * FF);
  u16*   kvb0  = (u16*)  alloc(sizeof(u16) * NTOK * DD);
  u16*   kvb1  = (u16*)  alloc(sizeof(u16) * NTOK * DD);
  u16*   kvb2  = (u16*)  alloc(sizeof(u16) * NTOK * DD);
  u16*   kvb3  = (u16*)  alloc(sizeof(u16) * NTOK * DD);
  u16*   KVc   = (u16*)  alloc(sizeof(u16) * 16 * NTOK * DD);
  float* xf    = (float*)alloc(sizeof(float) * NTOK * DD);
  u16*   xb    = (u16*)  alloc(sizeof(u16) * NTOK * DD);
  u16*   Qb    = (u16*)  alloc(sizeof(u16) * NTOK * DD);
  u16*   Kb    = (u16*)  alloc(sizeof(u16) * NTOK * DD);
  u16*   Vtb   = (u16*)  alloc(sizeof(u16) * NTOK * DD);
  u16*   scr   = (u16*)  alloc(sizeof(u16) * (size_t)BB * HH * TT * TT);
  u16*   attnb = (u16*)  alloc(sizeof(u16) * NTOK * DD);
  float* obuf  = (float*)alloc(sizeof(float) * NTOK * DD);
  u16*   hb    = (u16*)  alloc(sizeof(u16) * NTOK * FF);

  // ---- weight prep ----
  const dim3 tg(32, 32, 2);
  transpose_w_kernel<<<tg, 256, 0, stream>>>(Wq, WqkvS,          DD, DD, 5*D2, 0, 3*D2, 0, 1);
  transpose_w_kernel<<<tg, 256, 0, stream>>>(Wk, WqkvS + D2,     DD, DD, 5*D2, 0, 3*D2, 0, 1);
  transpose_w_kernel<<<tg, 256, 0, stream>>>(Wv, WqkvS + 2*D2,   DD, DD, 5*D2, 0, 3*D2, 0, 1);
  transpose_w_kernel<<<dim3(32,32,8), 256, 0, stream>>>(Wk + D2, WkvC,      DD, DD, 5*D2, D2, 8*D2, 2*D2, 4);
  transpose_w_kernel<<<dim3(32,32,8), 256, 0, stream>>>(Wv + D2, WkvC + D2, DD, DD, 5*D2, D2, 8*D2, 2*D2, 4);
  transpose_w_kernel<<<dim3(32,32,8), 256, 0, stream>>>(Wq + D2, WqC,       DD, DD, 5*D2, D2, 4*D2, D2,   4);
  transpose_w_kernel<<<dim3(32,32,10),256, 0, stream>>>(Wo, WoT,            DD, DD, D2, 0, D2, 0, 1);
  transpose_w_kernel<<<dim3(128,32,2),256, 0, stream>>>(W1, W1T, DD, FF, (long)DD*FF, 0, (long)DD*FF, 0, 1);
  transpose_w_kernel<<<dim3(32,128,2),256, 0, stream>>>(W2, W2T, FF, DD, (long)DD*FF, 0, (long)DD*FF, 0, 1);

  const int n4 = (int)(NTOK * DD / 4);
  f32_to_bf16_4<<<dim3(n4/256, 4, 1), 256, 0, stream>>>(
      g_db, g_con, g_usr, g_enc, kvb0, kvb1, kvb2, kvb3, n4);

  embed_kernel<<<(int)NTOK, 256, 0, stream>>>(emb, pvec, pose, obuf);
  ln_kernel<<<(int)NTOK, 256, 0, stream>>>(obuf, nullptr, xf, xb);

  // ---- precompute all cross-attention K/V (constant inputs) ----
  const u16* kvPtr[4] = {kvb0, kvb1, kvb2, kvb3};
  const long NB = (long)NTOK * DD;
  for (int ci = 0; ci < 4; ++ci){
    gemm_k<128,128,MODE_KV><<<dim3(8,16,4), 256, 0, stream>>>(
      kvPtr[ci], WkvC + (long)ci*2*D2,
      bk + (ci+1)*DD, bv + (ci+1)*DD, nullptr,
      nullptr, KVc + (long)ci*2*NB, nullptr, nullptr,
      DD, DD, DD, 0,
      0, 8*D2, D2, 2,
      8*NB, NB, 2, 5*DD,
      0, 1.0f);
  }

  const int modeTab[5] = {-1, 2, 1, 3, 0};

  for (int l = 0; l < 2; ++l){
    for (int i = 0; i < 5; ++i){
      const u16 *Kp, *Vp;
      if (i == 0){
        gemm_k<64,128,MODE_QKV><<<dim3(24,32,1), 256, 0, stream>>>(
          xb, WqkvS + (long)l*3*D2,
          bq + (size_t)l*5*DD, bk + (size_t)l*5*DD, bv + (size_t)l*5*DD,
          nullptr, Qb, Kb, Vtb,
          DD, DD, DD, 0,
          0, 0, 0, 1, 0, 0, 1, 0,
          0, 0.125f);
        Kp = Kb; Vp = Vtb;
      } else {
        const int ci = i - 1;
        gemm_k<64,128,MODE_Q><<<dim3(8,32,1), 256, 0, stream>>>(
          xb, WqC + (long)(l*4 + ci)*D2,
          bq + (size_t)(l*5 + i)*DD, nullptr, nullptr,
          nullptr, Qb, nullptr, nullptr,
          DD, DD, DD, 0,
          0, 0, 0, 1, 0, 0, 1, 0,
          0, 0.125f);
        Kp = KVc + ((long)l*4 + ci)*2*NB;
        Vp = Kp + NB;
      }
      // scores = Q @ K^T (batched over b*h), K = 64 -> single step
      gemm_k<128,128,MODE_BF16><<<dim3(4,4,64), 256, 0, stream>>>(
        Qb, Kp, nullptr, nullptr, nullptr,
        nullptr, scr, nullptr, nullptr,
        DHH, DHH, DHH, TT,
        (long)TT*DHH, (long)TT*DHH, 0, 1,
        (long)TT*TT, 0, 1, 0,
        0, 1.0f);
      softmax_kernel<<<BB*HH*TT/4, 256, 0, stream>>>(scr, cmask, modeTab[i]);
      // attn = P @ V -> [B*T][D]
      gemm_k<128,64,MODE_BF16><<<dim3(1,4,64), 256, 0, stream>>>(
        scr, Vp, nullptr, nullptr, nullptr,
        nullptr, attnb, nullptr, nullptr,
        TT, TT, TT, DD,
        (long)TT*TT, (long)DHH*TT, 0, 1,
        (long)TT*DD, DHH, 16, 0,
        0, 1.0f);
      // O-projection (f32 out for residual)
      gemm_k<64,128,MODE_F32><<<dim3(8,32,1), 256, 0, stream>>>(
        attnb, WoT + (long)(l*5 + i)*D2,
        bo + (size_t)(l*5 + i)*DD, nullptr, nullptr,
        obuf, nullptr, nullptr, nullptr,
        DD, DD, DD, DD,
        0, 0, 0, 1, 0, 0, 1, 0,
        0, 1.0f);
      ln_kernel<<<(int)NTOK, 256, 0, stream>>>(obuf, xf, xf, xb);
    }
    // FFN
    gemm_k<128,128,MODE_BF16><<<dim3(32,16,1), 256, 0, stream>>>(
      xb, W1T + (size_t)l*DD*FF,
      b1 + (size_t)l*FF, nullptr, nullptr,
      nullptr, hb, nullptr, nullptr,
      DD, DD, DD, FF,
      0, 0, 0, 1, 0, 0, 1, 0,
      1, 1.0f);
    gemm_k<64,128,MODE_F32><<<dim3(8,32,1), 256, 0, stream>>>(
      hb, W2T + (size_t)l*DD*FF,
      b2 + (size_t)l*DD, nullptr, nullptr,
      obuf, nullptr, nullptr, nullptr,
      FF, FF, FF, DD,
      0, 0, 0, 1, 0, 0, 1, 0,
      0, 1.0f);
    float* yf = (l == 1) ? out : xf;
    ln_kernel<<<(int)NTOK, 256, 0, stream>>>(obuf, xf, yf, xb);
  }
}

// Round 4
// 1067.484 us; speedup vs baseline: 3.8100x; 1.5913x over previous
//
#include <hip/hip_runtime.h>

// Problem constants (Bert4KGModel): B=4, T=S=512, D=1024, H=16, dh=64, F=4096, L=2
#define BB  4
#define TT  512
#define DD  1024
#define HH  16
#define DHH 64
#define FF  4096

typedef unsigned short u16;
typedef __attribute__((ext_vector_type(8))) short bfrag8;   // 8 bf16 (4 VGPRs)
typedef __attribute__((ext_vector_type(4))) float facc4;    // 4 f32 acc

__device__ __forceinline__ u16 f2bf(float f){
  unsigned u = __float_as_uint(f);
  unsigned r = u + 0x7fffu + ((u >> 16) & 1u);   // RNE
  return (u16)(r >> 16);
}
__device__ __forceinline__ float bf2f(u16 h){
  return __uint_as_float(((unsigned)h) << 16);
}

// async global->LDS, 16B per lane; LDS dest is wave-uniform base + lane*16
__device__ __forceinline__ void gload16(const u16* g, u16* l){
  __builtin_amdgcn_global_load_lds(
      (const __attribute__((address_space(1))) void*)g,
      (__attribute__((address_space(3))) void*)l, 16, 0, 0);
}

// counted vmcnt wait (literal immediates only)
template<int N> __device__ __forceinline__ void vwait(){
  static_assert(N==0 || N==4 || N==6 || N==8, "unsupported vmcnt literal");
  if constexpr (N==0) asm volatile("s_waitcnt vmcnt(0)" ::: "memory");
  else if constexpr (N==4) asm volatile("s_waitcnt vmcnt(4)" ::: "memory");
  else if constexpr (N==6) asm volatile("s_waitcnt vmcnt(6)" ::: "memory");
  else if constexpr (N==8) asm volatile("s_waitcnt vmcnt(8)" ::: "memory");
}

// ---------------------------------------------------------------------------
// Weight transpose + f32->bf16 with generalized z-mapping
// ---------------------------------------------------------------------------
__global__ __launch_bounds__(256) void transpose_w_kernel(
    const float* __restrict__ W, u16* __restrict__ Wt, int R, int C,
    long szs1, long szs2, long dzs1, long dzs2, int zdiv)
{
  __shared__ float tile[32][33];
  const int tx = threadIdx.x & 31, ty = threadIdx.x >> 5;   // 32 x 8
  const int z = blockIdx.z;
  const long so = (long)(z / zdiv) * szs1 + (long)(z % zdiv) * szs2;
  const long dzo = (long)(z / zdiv) * dzs1 + (long)(z % zdiv) * dzs2;
  const int c0 = blockIdx.x << 5, r0 = blockIdx.y << 5;
  #pragma unroll
  for (int i = 0; i < 4; ++i)
    tile[ty + i*8][tx] = W[so + (long)(r0 + ty + i*8)*C + c0 + tx];
  __syncthreads();
  #pragma unroll
  for (int i = 0; i < 4; ++i)
    Wt[dzo + (long)(c0 + ty + i*8)*R + r0 + tx] = f2bf(tile[tx][ty + i*8]);
}

// ---------------------------------------------------------------------------
// 4 buffers f32 -> bf16 in one launch
// ---------------------------------------------------------------------------
__global__ __launch_bounds__(256) void f32_to_bf16_4(
    const float* __restrict__ a0, const float* __restrict__ a1,
    const float* __restrict__ a2, const float* __restrict__ a3,
    u16* __restrict__ o0, u16* __restrict__ o1,
    u16* __restrict__ o2, u16* __restrict__ o3, int n4)
{
  const float* s; u16* d;
  switch (blockIdx.y){
    case 0: s = a0; d = o0; break;
    case 1: s = a1; d = o1; break;
    case 2: s = a2; d = o2; break;
    default: s = a3; d = o3; break;
  }
  int i = blockIdx.x * 256 + threadIdx.x;
  if (i >= n4) return;
  float4 v = ((const float4*)s)[i];
  ushort4 o;
  o.x = f2bf(v.x); o.y = f2bf(v.y); o.z = f2bf(v.z); o.w = f2bf(v.w);
  ((ushort4*)d)[i] = o;
}

// ---------------------------------------------------------------------------
// Embedding gather
// ---------------------------------------------------------------------------
__global__ __launch_bounds__(256) void embed_kernel(
    const float* __restrict__ emb, const int* __restrict__ pvec,
    const float* __restrict__ pos, float* __restrict__ out)
{
  const int row = blockIdx.x;
  const int i = threadIdx.x;
  const int idx = pvec[row];
  const int t = row & (TT - 1);
  float4 e = ((const float4*)(emb + (long)idx * DD))[i];
  float4 p = ((const float4*)(pos + (long)t * DD))[i];
  float4 o;
  o.x = e.x * 32.0f + p.x; o.y = e.y * 32.0f + p.y;
  o.z = e.z * 32.0f + p.z; o.w = e.w * 32.0f + p.w;
  ((float4*)(out + (long)row * DD))[i] = o;
}

// ---------------------------------------------------------------------------
// LayerNorm(a [+ res]) -> yf (f32, optional) and yb (bf16)
// ---------------------------------------------------------------------------
__global__ __launch_bounds__(256) void ln_kernel(
    const float* __restrict__ a, const float* __restrict__ res,
    float* __restrict__ yf, u16* __restrict__ yb)
{
  const int row = blockIdx.x;
  const int i = threadIdx.x;
  const int lane = i & 63, wid = i >> 6;
  float4 x = ((const float4*)(a + (long)row * DD))[i];
  if (res){
    float4 r4 = ((const float4*)(res + (long)row * DD))[i];
    x.x += r4.x; x.y += r4.y; x.z += r4.z; x.w += r4.w;
  }
  float s = x.x + x.y + x.z + x.w;
  #pragma unroll
  for (int o = 32; o; o >>= 1) s += __shfl_xor(s, o);
  __shared__ float red[4];
  if (lane == 0) red[wid] = s;
  __syncthreads();
  const float mean = (red[0] + red[1] + red[2] + red[3]) * (1.0f / DD);
  __syncthreads();
  const float dx = x.x - mean, dy = x.y - mean, dz = x.z - mean, dw = x.w - mean;
  float q = dx*dx + dy*dy + dz*dz + dw*dw;
  #pragma unroll
  for (int o = 32; o; o >>= 1) q += __shfl_xor(q, o);
  if (lane == 0) red[wid] = q;
  __syncthreads();
  const float var = (red[0] + red[1] + red[2] + red[3]) * (1.0f / DD);
  const float rstd = rsqrtf(var + 1e-5f);
  float4 y; y.x = dx*rstd; y.y = dy*rstd; y.z = dz*rstd; y.w = dw*rstd;
  if (yf) ((float4*)(yf + (long)row * DD))[i] = y;
  ushort4 o4; o4.x = f2bf(y.x); o4.y = f2bf(y.y); o4.z = f2bf(y.z); o4.w = f2bf(y.w);
  ((ushort4*)(yb + (long)row * DD))[i] = o4;
}

// ---------------------------------------------------------------------------
// Flash attention: one block per (q-tile 64, b*h). 4 waves x 16 q-rows.
// Q [bh][512][64] bf16 (pre-scaled 1/8), K [bh][512][64], V^T [bh][64][512].
// Online softmax in C-frags; P via wave-private swizzled LDS; counted-vmcnt
// double-buffered K/V staging. CAUSAL: col<=row; else bias from cmask!=mode.
// Output: O[b*512+t][1024] at col h*64.
// ---------------------------------------------------------------------------
template<bool CAUSAL>
__global__ __launch_bounds__(256, 2) void flash_kernel(
    const u16* __restrict__ Q, const u16* __restrict__ Kt,
    const u16* __restrict__ Vt, const int* __restrict__ cmask, int mode,
    u16* __restrict__ O)
{
  __shared__ __align__(16) u16 Ks[2][64*64];
  __shared__ __align__(16) u16 Vs[2][64*64];
  __shared__ __align__(16) u16 Ps[4*16*64];
  __shared__ float biasS[512];

  // XCD swizzle: all 8 q-tiles of one head land on one XCD (K/V L2 reuse)
  const int fid = blockIdx.y * 8 + blockIdx.x;          // 0..511
  const int lid = (fid & 7) * 64 + (fid >> 3);
  const int qt = lid & 7;
  const int bh = lid >> 3;
  const int b = bh >> 4, h = bh & 15;

  const int tid = threadIdx.x, lane = tid & 63, wid = tid >> 6;
  const int fr = lane & 15, kg = lane >> 4;

  if (!CAUSAL){
    #pragma unroll
    for (int r = 0; r < 2; ++r){
      const int c = r * 256 + tid;
      biasS[c] = (cmask[b * 512 + c] != mode) ? 0.0f : -1e20f;
    }
  }

  const long base = (long)bh * (512 * 64);
  const u16* qrow = Q + base + (long)(qt*64 + wid*16 + fr) * 64;
  const bfrag8 aq0 = *(const bfrag8*)(qrow + kg*8);
  const bfrag8 aq1 = *(const bfrag8*)(qrow + 32 + kg*8);

  const int srow = tid >> 3;                         // 0..31
  const int gcol = ((tid & 7) ^ (srow & 7)) * 8;     // pre-swizzled source chunk

  auto stageKV = [&](int buf, int kt){
    u16* Kd = Ks[buf] + wid * 512;
    u16* Vd = Vs[buf] + wid * 512;
    #pragma unroll
    for (int p = 0; p < 2; ++p)
      gload16(Kt + base + (long)(kt*64 + p*32 + srow) * 64 + gcol, Kd + p*2048);
    #pragma unroll
    for (int p = 0; p < 2; ++p)
      gload16(Vt + base + (long)(p*32 + srow) * 512 + kt*64 + gcol, Vd + p*2048);
  };

  float mrow[4], lrow[4];
  #pragma unroll
  for (int r = 0; r < 4; ++r){ mrow[r] = -3e38f; lrow[r] = 0.0f; }
  facc4 accO[4] = {};
  const facc4 z4 = {0.0f, 0.0f, 0.0f, 0.0f};

  const int NT = CAUSAL ? (qt + 1) : 8;   // causal: skip fully-masked tiles
  stageKV(0, 0);
  if (NT > 1){ stageKV(1, 1); vwait<4>(); }
  else vwait<0>();
  __builtin_amdgcn_s_barrier();

  u16* Pw = Ps + wid * 1024;

  for (int kt = 0; kt < NT; ++kt){
    const int cur = kt & 1;
    bfrag8 bk[4][2], bv[4][2];
    #pragma unroll
    for (int j = 0; j < 4; ++j)
      #pragma unroll
      for (int c2 = 0; c2 < 2; ++c2){
        const int po = (((c2*4 + kg) ^ (fr & 7)) * 8);
        bk[j][c2] = *(const bfrag8*)&Ks[cur][(j*16 + fr)*64 + po];
        bv[j][c2] = *(const bfrag8*)&Vs[cur][(j*16 + fr)*64 + po];
      }
    __builtin_amdgcn_sched_barrier(0);
    __builtin_amdgcn_s_barrier();                 // all waves read buf[cur]
    if (kt + 2 < NT){ stageKV(cur, kt + 2); vwait<4>(); }
    else vwait<0>();                              // stage(kt+1) landed
    __builtin_amdgcn_s_barrier();                 // ...for every wave

    // QK^T (rows = q, cols = kpos)
    facc4 sc[4];
    #pragma unroll
    for (int j = 0; j < 4; ++j){
      sc[j] = __builtin_amdgcn_mfma_f32_16x16x32_bf16(aq0, bk[j][0], z4, 0, 0, 0);
      sc[j] = __builtin_amdgcn_mfma_f32_16x16x32_bf16(aq1, bk[j][1], sc[j], 0, 0, 0);
    }
    // mask
    if (CAUSAL){
      const int rowb = qt*64 + wid*16 + kg*4;
      #pragma unroll
      for (int j = 0; j < 4; ++j){
        const int col = kt*64 + j*16 + fr;
        #pragma unroll
        for (int r = 0; r < 4; ++r)
          if (col > rowb + r) sc[j][r] = -1e20f;
      }
    } else {
      #pragma unroll
      for (int j = 0; j < 4; ++j){
        const float bval = biasS[kt*64 + j*16 + fr];
        #pragma unroll
        for (int r = 0; r < 4; ++r) sc[j][r] += bval;
      }
    }
    // online softmax (per-lane rows kg*4+rr; reduce across fr lanes)
    float tmax[4];
    #pragma unroll
    for (int r = 0; r < 4; ++r)
      tmax[r] = fmaxf(fmaxf(sc[0][r], sc[1][r]), fmaxf(sc[2][r], sc[3][r]));
    #pragma unroll
    for (int o = 1; o < 16; o <<= 1)
      #pragma unroll
      for (int r = 0; r < 4; ++r)
        tmax[r] = fmaxf(tmax[r], __shfl_xor(tmax[r], o));
    float fac[4];
    #pragma unroll
    for (int r = 0; r < 4; ++r){
      const float mn = fmaxf(mrow[r], tmax[r]);
      fac[r] = __expf(mrow[r] - mn);
      mrow[r] = mn;
    }
    float tsum[4] = {0.0f, 0.0f, 0.0f, 0.0f};
    #pragma unroll
    for (int j = 0; j < 4; ++j)
      #pragma unroll
      for (int r = 0; r < 4; ++r){
        const float p = __expf(sc[j][r] - mrow[r]);
        sc[j][r] = p; tsum[r] += p;
      }
    #pragma unroll
    for (int o = 1; o < 16; o <<= 1)
      #pragma unroll
      for (int r = 0; r < 4; ++r) tsum[r] += __shfl_xor(tsum[r], o);
    #pragma unroll
    for (int r = 0; r < 4; ++r) lrow[r] = lrow[r]*fac[r] + tsum[r];
    #pragma unroll
    for (int f = 0; f < 4; ++f)
      #pragma unroll
      for (int r = 0; r < 4; ++r) accO[f][r] *= fac[r];

    // P -> wave-private LDS (chunk-swizzled), read back as A-frags
    #pragma unroll
    for (int j = 0; j < 4; ++j)
      #pragma unroll
      for (int r = 0; r < 4; ++r){
        const int row = kg*4 + r;
        const int col = j*16 + fr;
        Pw[row*64 + (((col >> 3) ^ (row & 7)) * 8) + (col & 7)] = f2bf(sc[j][r]);
      }
    bfrag8 ap[2];
    #pragma unroll
    for (int c2 = 0; c2 < 2; ++c2)
      ap[c2] = *(const bfrag8*)&Pw[fr*64 + (((c2*4 + kg) ^ (fr & 7)) * 8)];
    #pragma unroll
    for (int f = 0; f < 4; ++f){
      accO[f] = __builtin_amdgcn_mfma_f32_16x16x32_bf16(ap[0], bv[f][0], accO[f], 0, 0, 0);
      accO[f] = __builtin_amdgcn_mfma_f32_16x16x32_bf16(ap[1], bv[f][1], accO[f], 0, 0, 0);
    }
  }

  // epilogue: divide by row sum, write [b*512+t][1024] at col h*64
  #pragma unroll
  for (int f = 0; f < 4; ++f)
    #pragma unroll
    for (int r = 0; r < 4; ++r){
      const int row = qt*64 + wid*16 + kg*4 + r;
      const int col = h*64 + f*16 + fr;
      O[(long)(b*512 + row) * 1024 + col] = f2bf(accO[f][r] / lrow[r]);
    }
}

// ---------------------------------------------------------------------------
// bf16 MFMA GEMM, BK=64, double-buffered LDS, counted-vmcnt pipeline,
// XCD-aware block swizzle. C = alpha*(A·B^T + bias).
// ---------------------------------------------------------------------------
#define MODE_F32  0
#define MODE_BF16 1
#define MODE_QKV  3
#define MODE_KV   4
#define MODE_Q    5

__device__ __forceinline__ long qk_off(int gm, int gn){   // [b,h,t,d]
  return (((long)(gm >> 9) * HH + (gn >> 6)) * TT + (gm & (TT-1))) * DHH + (gn & (DHH-1));
}
__device__ __forceinline__ long vt_off(int gm, int gn){   // [b,h,d,s]
  return (((long)(gm >> 9) * HH + (gn >> 6)) * DHH + (gn & (DHH-1))) * TT + (gm & (TT-1));
}

template<int BM, int BN, int MODE>
__global__ __launch_bounds__(256, 2) void gemm_k(
    const u16* __restrict__ A, const u16* __restrict__ B,
    const float* __restrict__ bias0, const float* __restrict__ bias1,
    const float* __restrict__ bias2,
    float* __restrict__ Cf, u16* __restrict__ Cb0,
    u16* __restrict__ Cb1, u16* __restrict__ Cb2,
    int K, int lda, int ldb, int ldc,
    long zsA, long zsB1, long zsB2, int zdivB,
    long czs1, long czs2, int zdivC, long bzs,
    int relu, float alpha)
{
  constexpr int BK = 64;
  constexpr int ASZ = BM * BK, BSZ = BN * BK;           // u16 per buffer
  __shared__ __align__(16) u16 As[2 * ASZ];
  __shared__ __align__(16) u16 Bs[2 * BSZ];

  // XCD-aware bijective block swizzle (all grids are %8 == 0)
  const int gx = gridDim.x, gy = gridDim.y;
  const int nwg = gx * gy * gridDim.z;
  const int fid = (blockIdx.z * gy + blockIdx.y) * gx + blockIdx.x;
  const int cpx = nwg >> 3;
  const int lid = (fid & 7) * cpx + (fid >> 3);
  const int bx = lid % gx;
  const int rem = lid / gx;
  const int by = rem % gy;
  const int z  = rem / gy;

  const u16* Ab = A + (long)z * zsA;
  const u16* Bb = B + (long)(z / zdivB) * zsB1 + (long)(z % zdivB) * zsB2;
  const long cbase = (long)(z / zdivC) * czs1 + (long)(z % zdivC) * czs2;
  const int tid = threadIdx.x, lane = tid & 63, wid = tid >> 6;
  const int m0 = by * BM, n0 = bx * BN;
  constexpr int WGN = (BN >= 128) ? 2 : 1, WGM = 4 / WGN;
  constexpr int TMW = BM / WGM, TNW = BN / WGN;
  constexpr int FM = TMW / 16, FN = TNW / 16;
  const int wm = (wid / WGN) * TMW, wn = (wid % WGN) * TNW;
  const int fr = lane & 15, kg = lane >> 4;
  facc4 acc[FM][FN] = {};

  // staging: pass = 32 rows (4KB); thread t -> row t>>3, phys chunk t&7;
  // global chunk pre-swizzled: LDS[r][c] = G[r][c^(r&7)]
  const int srow = tid >> 3;
  const int gcol = (((tid & 7) ^ (srow & 7)) * 8);
  constexpr int AP = BM / 32, BP = BN / 32;
  constexpr int LPS = AP + BP;                     // VMEM instrs per stage per wave

  auto stage = [&](int buf, int k0){
    u16* Ad = As + buf * ASZ + wid * 512;
    u16* Bd = Bs + buf * BSZ + wid * 512;
    #pragma unroll
    for (int p = 0; p < AP; ++p)
      gload16(Ab + (long)(m0 + p*32 + srow) * lda + (k0 + gcol), Ad + p*2048);
    #pragma unroll
    for (int p = 0; p < BP; ++p)
      gload16(Bb + (long)(n0 + p*32 + srow) * ldb + (k0 + gcol), Bd + p*2048);
  };

  const int nsteps = K / BK;
  stage(0, 0);
  if (nsteps > 1){ stage(1, BK); vwait<LPS>(); }
  else vwait<0>();
  __builtin_amdgcn_s_barrier();

  for (int s = 0; s < nsteps; ++s){
    const int cur = s & 1;
    const u16* Ar = As + cur * ASZ;
    const u16* Br = Bs + cur * BSZ;
    bfrag8 af[FM][2], bfv[FN][2];
    #pragma unroll
    for (int i = 0; i < FM; ++i)
      #pragma unroll
      for (int c2 = 0; c2 < 2; ++c2)
        af[i][c2] = *(const bfrag8*)&Ar[(wm + i*16 + fr) * 64 + (((c2*4 + kg) ^ (fr & 7)) * 8)];
    #pragma unroll
    for (int j = 0; j < FN; ++j)
      #pragma unroll
      for (int c2 = 0; c2 < 2; ++c2)
        bfv[j][c2] = *(const bfrag8*)&Br[(wn + j*16 + fr) * 64 + (((c2*4 + kg) ^ (fr & 7)) * 8)];
    __builtin_amdgcn_sched_barrier(0);
    __builtin_amdgcn_s_barrier();                 // all waves done reading buf[cur]
    if (s + 2 < nsteps){ stage(cur, (s + 2) * BK); vwait<LPS>(); }
    else vwait<0>();                              // stage(s+1) landed
    __builtin_amdgcn_s_barrier();                 // ...for every wave
    #pragma unroll
    for (int i = 0; i < FM; ++i)
      #pragma unroll
      for (int j = 0; j < FN; ++j){
        acc[i][j] = __builtin_amdgcn_mfma_f32_16x16x32_bf16(af[i][0], bfv[j][0], acc[i][j], 0, 0, 0);
        acc[i][j] = __builtin_amdgcn_mfma_f32_16x16x32_bf16(af[i][1], bfv[j][1], acc[i][j], 0, 0, 0);
      }
  }

  // Epilogue. C/D frag layout: col = fr, row = kg*4 + rr.
  #pragma unroll
  for (int i = 0; i < FM; ++i){
    #pragma unroll
    for (int j = 0; j < FN; ++j){
      const int gn = n0 + wn + j*16 + fr;
      #pragma unroll
      for (int rr = 0; rr < 4; ++rr){
        const int gm = m0 + wm + i*16 + kg*4 + rr;
        float v = acc[i][j][rr];
        if constexpr (MODE == MODE_F32){
          v = (v + (bias0 ? bias0[gn] : 0.0f)) * alpha;
          if (relu) v = fmaxf(v, 0.0f);
          Cf[cbase + (long)gm * ldc + gn] = v;
        } else if constexpr (MODE == MODE_BF16){
          v = (v + (bias0 ? bias0[gn] : 0.0f)) * alpha;
          if (relu) v = fmaxf(v, 0.0f);
          Cb0[cbase + (long)gm * ldc + gn] = f2bf(v);
        } else if constexpr (MODE == MODE_QKV){
          const int sect = gn >> 10, nn = gn & (DD - 1);
          if (sect == 0)      Cb0[qk_off(gm, nn)] = f2bf((v + bias0[nn]) * alpha);
          else if (sect == 1) Cb1[qk_off(gm, nn)] = f2bf(v + bias1[nn]);
          else                Cb2[vt_off(gm, nn)] = f2bf(v + bias2[nn]);
        } else if constexpr (MODE == MODE_Q){
          Cb0[qk_off(gm, gn)] = f2bf((v + bias0[gn]) * alpha);
        } else {  // MODE_KV
          const float* bp = ((z & 1) ? bias1 : bias0) + (long)(z >> 1) * bzs;
          const float vb = v + bp[gn];
          if (z & 1) Cb0[cbase + vt_off(gm, gn)] = f2bf(vb);
          else       Cb0[cbase + qk_off(gm, gn)] = f2bf(vb);
        }
      }
    }
  }
}

// ---------------------------------------------------------------------------
extern "C" void kernel_launch(void* const* d_in, const int* in_sizes, int n_in,
                              void* d_out, int out_size, void* d_ws, size_t ws_size,
                              hipStream_t stream)
{
  (void)in_sizes; (void)n_in; (void)out_size; (void)ws_size;
  const float* emb   = (const float*)d_in[0];
  const int*   pvec  = (const int*)d_in[1];
  const float* g_enc = (const float*)d_in[2];
  const float* g_con = (const float*)d_in[3];
  const float* g_db  = (const float*)d_in[4];
  const float* g_usr = (const float*)d_in[5];
  const int*   cmask = (const int*)d_in[6];
  const float* pose  = (const float*)d_in[7];
  const float* Wq = (const float*)d_in[8];
  const float* bq = (const float*)d_in[9];
  const float* Wk = (const float*)d_in[10];
  const float* bk = (const float*)d_in[11];
  const float* Wv = (const float*)d_in[12];
  const float* bv = (const float*)d_in[13];
  const float* Wo = (const float*)d_in[14];
  const float* bo = (const float*)d_in[15];
  const float* W1 = (const float*)d_in[16];
  const float* b1 = (const float*)d_in[17];
  const float* W2 = (const float*)d_in[18];
  const float* b2 = (const float*)d_in[19];
  float* out = (float*)d_out;

  const size_t NTOK = (size_t)BB * TT;   // 2048
  const long D2 = (long)DD * DD;

  char* wp = (char*)d_ws;
  auto alloc = [&](size_t bytes) -> char* {
    char* p = wp;
    wp += (bytes + 255) & ~(size_t)255;
    return p;
  };
  u16*   WqkvS = (u16*)  alloc(sizeof(u16) * 2 * 3 * D2);
  u16*   WkvC  = (u16*)  alloc(sizeof(u16) * 2 * 4 * 2 * D2);
  u16*   WqC   = (u16*)  alloc(sizeof(u16) * 2 * 4 * D2);
  u16*   WoT   = (u16*)  alloc(sizeof(u16) * 10 * D2);
  u16*   W1T   = (u16*)  alloc(sizeof(u16) * 2 * DD * FF);
  u16*   W2T   = (u16*)  alloc(sizeof(u16) * 2 * DD * FF);
  u16*   kvb0  = (u16*)  alloc(sizeof(u16) * NTOK * DD);
  u16*   kvb1  = (u16*)  alloc(sizeof(u16) * NTOK * DD);
  u16*   kvb2  = (u16*)  alloc(sizeof(u16) * NTOK * DD);
  u16*   kvb3  = (u16*)  alloc(sizeof(u16) * NTOK * DD);
  u16*   KVc   = (u16*)  alloc(sizeof(u16) * 16 * NTOK * DD);
  float* xf    = (float*)alloc(sizeof(float) * NTOK * DD);
  u16*   xb    = (u16*)  alloc(sizeof(u16) * NTOK * DD);
  u16*   Qb    = (u16*)  alloc(sizeof(u16) * NTOK * DD);
  u16*   Kb    = (u16*)  alloc(sizeof(u16) * NTOK * DD);
  u16*   Vtb   = (u16*)  alloc(sizeof(u16) * NTOK * DD);
  u16*   attnb = (u16*)  alloc(sizeof(u16) * NTOK * DD);
  float* obuf  = (float*)alloc(sizeof(float) * NTOK * DD);
  u16*   hb    = (u16*)  alloc(sizeof(u16) * NTOK * FF);

  // ---- weight prep ----
  const dim3 tg(32, 32, 2);
  transpose_w_kernel<<<tg, 256, 0, stream>>>(Wq, WqkvS,          DD, DD, 5*D2, 0, 3*D2, 0, 1);
  transpose_w_kernel<<<tg, 256, 0, stream>>>(Wk, WqkvS + D2,     DD, DD, 5*D2, 0, 3*D2, 0, 1);
  transpose_w_kernel<<<tg, 256, 0, stream>>>(Wv, WqkvS + 2*D2,   DD, DD, 5*D2, 0, 3*D2, 0, 1);
  transpose_w_kernel<<<dim3(32,32,8), 256, 0, stream>>>(Wk + D2, WkvC,      DD, DD, 5*D2, D2, 8*D2, 2*D2, 4);
  transpose_w_kernel<<<dim3(32,32,8), 256, 0, stream>>>(Wv + D2, WkvC + D2, DD, DD, 5*D2, D2, 8*D2, 2*D2, 4);
  transpose_w_kernel<<<dim3(32,32,8), 256, 0, stream>>>(Wq + D2, WqC,       DD, DD, 5*D2, D2, 4*D2, D2,   4);
  transpose_w_kernel<<<dim3(32,32,10),256, 0, stream>>>(Wo, WoT,            DD, DD, D2, 0, D2, 0, 1);
  transpose_w_kernel<<<dim3(128,32,2),256, 0, stream>>>(W1, W1T, DD, FF, (long)DD*FF, 0, (long)DD*FF, 0, 1);
  transpose_w_kernel<<<dim3(32,128,2),256, 0, stream>>>(W2, W2T, FF, DD, (long)DD*FF, 0, (long)DD*FF, 0, 1);

  const int n4 = (int)(NTOK * DD / 4);
  f32_to_bf16_4<<<dim3(n4/256, 4, 1), 256, 0, stream>>>(
      g_db, g_con, g_usr, g_enc, kvb0, kvb1, kvb2, kvb3, n4);

  embed_kernel<<<(int)NTOK, 256, 0, stream>>>(emb, pvec, pose, obuf);
  ln_kernel<<<(int)NTOK, 256, 0, stream>>>(obuf, nullptr, xf, xb);

  // ---- precompute all cross-attention K/V (constant inputs) ----
  const u16* kvPtr[4] = {kvb0, kvb1, kvb2, kvb3};
  const long NB = (long)NTOK * DD;
  for (int ci = 0; ci < 4; ++ci){
    gemm_k<128,128,MODE_KV><<<dim3(8,16,4), 256, 0, stream>>>(
      kvPtr[ci], WkvC + (long)ci*2*D2,
      bk + (ci+1)*DD, bv + (ci+1)*DD, nullptr,
      nullptr, KVc + (long)ci*2*NB, nullptr, nullptr,
      DD, DD, DD, 0,
      0, 8*D2, D2, 2,
      8*NB, NB, 2, 5*DD,
      0, 1.0f);
  }

  const int modeTab[5] = {-1, 2, 1, 3, 0};

  for (int l = 0; l < 2; ++l){
    for (int i = 0; i < 5; ++i){
      const u16 *Kp, *Vp;
      if (i == 0){
        gemm_k<64,128,MODE_QKV><<<dim3(24,32,1), 256, 0, stream>>>(
          xb, WqkvS + (long)l*3*D2,
          bq + (size_t)l*5*DD, bk + (size_t)l*5*DD, bv + (size_t)l*5*DD,
          nullptr, Qb, Kb, Vtb,
          DD, DD, DD, 0,
          0, 0, 0, 1, 0, 0, 1, 0,
          0, 0.125f);
        Kp = Kb; Vp = Vtb;
      } else {
        const int ci = i - 1;
        gemm_k<64,128,MODE_Q><<<dim3(8,32,1), 256, 0, stream>>>(
          xb, WqC + (long)(l*4 + ci)*D2,
          bq + (size_t)(l*5 + i)*DD, nullptr, nullptr,
          nullptr, Qb, nullptr, nullptr,
          DD, DD, DD, 0,
          0, 0, 0, 1, 0, 0, 1, 0,
          0, 0.125f);
        Kp = KVc + ((long)l*4 + ci)*2*NB;
        Vp = Kp + NB;
      }
      // fused attention (QK^T + masked softmax + PV)
      if (i == 0)
        flash_kernel<true><<<dim3(8,64), 256, 0, stream>>>(
            Qb, Kp, Vp, cmask, 0, attnb);
      else
        flash_kernel<false><<<dim3(8,64), 256, 0, stream>>>(
            Qb, Kp, Vp, cmask, modeTab[i], attnb);
      // O-projection (f32 out for residual)
      gemm_k<64,128,MODE_F32><<<dim3(8,32,1), 256, 0, stream>>>(
        attnb, WoT + (long)(l*5 + i)*D2,
        bo + (size_t)(l*5 + i)*DD, nullptr, nullptr,
        obuf, nullptr, nullptr, nullptr,
        DD, DD, DD, DD,
        0, 0, 0, 1, 0, 0, 1, 0,
        0, 1.0f);
      ln_kernel<<<(int)NTOK, 256, 0, stream>>>(obuf, xf, xf, xb);
    }
    // FFN
    gemm_k<128,128,MODE_BF16><<<dim3(32,16,1), 256, 0, stream>>>(
      xb, W1T + (size_t)l*DD*FF,
      b1 + (size_t)l*FF, nullptr, nullptr,
      nullptr, hb, nullptr, nullptr,
      DD, DD, DD, FF,
      0, 0, 0, 1, 0, 0, 1, 0,
      1, 1.0f);
    gemm_k<64,128,MODE_F32><<<dim3(8,32,1), 256, 0, stream>>>(
      hb, W2T + (size_t)l*DD*FF,
      b2 + (size_t)l*DD, nullptr, nullptr,
      obuf, nullptr, nullptr, nullptr,
      FF, FF, FF, DD,
      0, 0, 0, 1, 0, 0, 1, 0,
      0, 1.0f);
    float* yf = (l == 1) ? out : xf;
    ln_kernel<<<(int)NTOK, 256, 0, stream>>>(obuf, xf, yf, xb);
  }
}